// Round 1
// baseline (512.027 us; speedup 1.0000x reference)
//
#include <hip/hip_runtime.h>

// HKSABlock on MI355X (gfx950). Round 8: gates GEMM ported to the 256x256
// counted-vmcnt phase-interleaved structure (T1+T2+T3+T4+T5 stack):
//   - BK=64 K-tiles split into 2 K-halves x 2 output-halves = 4 phases;
//     per phase: 8 ds_read_b128 || stage one 16KB piece || 16 MFMA (setprio).
//   - vmcnt(4)+raw s_barrier twice per K-tile (never vmcnt(0) in loop);
//     2 pieces (4 loads) always in flight across barriers.
//   - LDS XOR slot-swizzle (slot ^= (row&3)^((row>>2)&3)) with linear
//     global_load_lds dest + pre-swizzled global source (rule 21); the XOR
//     collapses to a per-lane constant on the read side.
//   - bijective XCD swizzle: 72 blocks/XCD = 9-wide bx band, by innermost.
// Everything else (qkv+RoPE GEMM, attention, scan) unchanged from R7.
// B=2, T=1024, D=1024, NH=16, HD=64, H=64, M=16.

typedef unsigned short u16;
typedef unsigned int   u32;
typedef __bf16 bf16x8 __attribute__((ext_vector_type(8)));
typedef float  f32x4  __attribute__((ext_vector_type(4)));

#define B_  2
#define T_  1024
#define D_  1024
#define NH_ 16
#define HD_ 64
#define H_  64
#define M_  16

__device__ __forceinline__ float b2f(u16 u) {
    return __uint_as_float(((u32)u) << 16);
}
__device__ __forceinline__ u16 f2b(float f) {
    u32 u = __float_as_uint(f);
    u32 r = (u + 0x7FFFu + ((u >> 16) & 1u)) >> 16;  // RNE
    return (u16)r;
}
__device__ __forceinline__ float blo(u32 u) { return __uint_as_float(u << 16); }
__device__ __forceinline__ float bhi(u32 u) { return __uint_as_float(u & 0xFFFF0000u); }

// Async global->LDS, 16 B per lane. LDS dest must be wave-uniform base.
__device__ __forceinline__ void stage16(const void* gp, void* lp) {
    typedef __attribute__((address_space(1))) const unsigned int GU;
    typedef __attribute__((address_space(3))) unsigned int LU;
    __builtin_amdgcn_global_load_lds((GU*)gp, (LU*)lp, 16, 0, 0);
}

// ---------------------------------------------------------------------------
// Generic MFMA GEMM: C[M,N] = A[M,K] * Bt[N,K]^T  (A,Bt bf16 row-major).
// 4 waves: wr = w>>1 (m-half), wc = w&1 (n-half). MT = BM/32, NT = BN/32.
// MODE 0: C fp32 (+ optional fp32 addend). MODE 1: C bf16.
// MODE 2: bf16 scatter into o_mat[(b*T + row)*1024 + h*64 + col], z = b*16+h.
// MODE 6: qkv + fused RoPE. N=3072; region = n0>>10 (0=Q,1=K,2=V). Each wave
//         owns one head's 64 cols; RoPE pair (i,i+32) = acc nt and nt+2.
//         Writes Qb(Cout)/Kb(Cout2)/Vb(Cout3) bf16 in (b,h,t,d).
// CAUSAL: skip blocks with n0 > m0+BM-1. TRUNCK: K truncated to m0+BM.
// ---------------------------------------------------------------------------
template<int BM, int BN, int BK, int MODE, bool TRUNCK, bool CAUSAL, int SWZ>
__global__ __launch_bounds__(256) void gemm_bt(
    const u16* __restrict__ A, const u16* __restrict__ Bt,
    void* __restrict__ Cout, void* __restrict__ Cout2, void* __restrict__ Cout3,
    const float* __restrict__ addend,
    int M, int N, int K, long strideA, long strideB, long strideC)
{
    constexpr int MT = BM / 32;
    constexpr int NT = BN / 32;
    constexpr int KCH = BK / 8;                  // 16B slots per row
    const int z  = blockIdx.z;
    int bx = blockIdx.x, by = blockIdx.y;
    if (SWZ == 2) {
        int f = by * gridDim.x + bx;
        int xcd = f & 7, k = f >> 3;
        by = k & 15;                             // by innermost per XCD
        bx = xcd * (gridDim.x >> 3) + (k >> 4);  // band per XCD
    }
    const int m0 = by * BM;
    const int n0 = bx * BN;
    if (CAUSAL && n0 > m0 + BM - 1) return;
    const int Keff = TRUNCK ? (K < m0 + BM ? K : m0 + BM) : K;

    const u16* Ab = A  + (size_t)z * (size_t)strideA;
    const u16* Bb = Bt + (size_t)z * (size_t)strideB;

    __shared__ alignas(16) u16 As[BM * BK];
    __shared__ alignas(16) u16 Bs[BN * BK];

    const int tid  = threadIdx.x;
    const int lane = tid & 63, w = tid >> 6;
    const int wr = w >> 1, wc = w & 1;
    const int quad = lane >> 4, l16 = lane & 15;

    f32x4 acc[MT][NT] = {};

    constexpr int AITER = (BM * BK / 8) / 256;
    constexpr int BITER = (BN * BK / 8) / 256;

    for (int k0 = 0; k0 < Keff; k0 += BK) {
        #pragma unroll
        for (int it = 0; it < AITER; ++it) {
            int c = it * 256 + tid;
            int m = c / KCH, kc = c % KCH;
            stage16(Ab + (size_t)(m0 + m) * K + k0 + kc * 8,
                    &As[(it * 256 + w * 64) * 8]);
        }
        #pragma unroll
        for (int it = 0; it < BITER; ++it) {
            int c = it * 256 + tid;
            int n = c / KCH, kc = c % KCH;
            stage16(Bb + (size_t)(n0 + n) * K + k0 + kc * 8,
                    &Bs[(it * 256 + w * 64) * 8]);
        }
        __syncthreads();

        #pragma unroll
        for (int kk = 0; kk < BK; kk += 32) {
            bf16x8 af[MT], bfr[NT];
            #pragma unroll
            for (int mt = 0; mt < MT; ++mt)
                af[mt] = *(const bf16x8*)&As[(wr * (BM / 2) + mt * 16 + l16) * BK + kk + quad * 8];
            #pragma unroll
            for (int nt = 0; nt < NT; ++nt)
                bfr[nt] = *(const bf16x8*)&Bs[(wc * (BN / 2) + nt * 16 + l16) * BK + kk + quad * 8];
            #pragma unroll
            for (int mt = 0; mt < MT; ++mt)
                #pragma unroll
                for (int nt = 0; nt < NT; ++nt)
                    acc[mt][nt] = __builtin_amdgcn_mfma_f32_16x16x32_bf16(
                        af[mt], bfr[nt], acc[mt][nt], 0, 0, 0);
        }
        __syncthreads();
    }

    // Epilogue. C/D layout: col = lane&15, row = (lane>>4)*4 + reg  [m89]
    if (MODE == 6) {
        // dedicated RoPE epilogue (NT==4, BN==128 required)
        const int reg = n0 >> 10;                      // 0=Q, 1=K, 2=V
        const int hh  = ((n0 & 1023) >> 6) + wc;       // head
        #pragma unroll
        for (int mt = 0; mt < MT; ++mt) {
            #pragma unroll
            for (int r = 0; r < 4; ++r) {
                int row = m0 + wr * (BM / 2) + mt * 16 + quad * 4 + r;
                int t = row & (T_ - 1), bb = row >> 10;
                size_t obase = ((size_t)(bb * NH_ + hh) * T_ + t) * HD_;
                if (reg == 2) {
                    #pragma unroll
                    for (int nt = 0; nt < 4; ++nt)
                        ((u16*)Cout3)[obase + nt * 16 + l16] = f2b(acc[mt][nt][r]);
                } else {
                    u16* dst = (reg == 0) ? (u16*)Cout : (u16*)Cout2;
                    #pragma unroll
                    for (int nt = 0; nt < 2; ++nt) {
                        int i = nt * 16 + l16;
                        float ang = (float)t * exp2f(-(float)i * 0.41524101186092034f);
                        float sn, cs;
                        sincosf(ang, &sn, &cs);
                        float q1 = acc[mt][nt][r], q2 = acc[mt][nt + 2][r];
                        dst[obase + i]      = f2b(q1 * cs - q2 * sn);
                        dst[obase + i + 32] = f2b(q2 * cs + q1 * sn);
                    }
                }
            }
        }
        return;
    }
    #pragma unroll
    for (int mt = 0; mt < MT; ++mt) {
        #pragma unroll
        for (int nt = 0; nt < NT; ++nt) {
            #pragma unroll
            for (int r = 0; r < 4; ++r) {
                int row = m0 + wr * (BM / 2) + mt * 16 + quad * 4 + r;
                int col = n0 + wc * (BN / 2) + nt * 16 + l16;
                float val = acc[mt][nt][r];
                if (MODE == 0) {
                    if (addend) val += addend[(size_t)row * N + col];
                    ((float*)Cout)[(size_t)z * (size_t)strideC + (size_t)row * N + col] = val;
                } else if (MODE == 1) {
                    ((u16*)Cout)[(size_t)z * (size_t)strideC + (size_t)row * N + col] = f2b(val);
                } else if (MODE == 2) {
                    size_t idx = ((size_t)(z >> 4) * T_ + row) * (size_t)D_ + (z & 15) * HD_ + col;
                    ((u16*)Cout)[idx] = f2b(val);
                }
            }
        }
    }
}

// ---------------------------------------------------------------------------
// gates+w_v GEMM, 256x256 tile, counted-vmcnt 4-phase schedule.
// C[2048, 18432] = h2[2048,1024] x waT[18432,1024]^T.
// 8 waves (2 m x 4 n), wave tile 128x64; BK=64 as 2 K-half pieces of 256x32.
// LDS: sA/sB [dbuf][khalf][256*32] = 128 KB total -> 1 block/CU.
// Swizzle: 16B slot ^= (row&3)^((row>>2)&3)  (even bank spread for b128;
// per-lane constant on reads since fragment rows = 16*base + l16).
// Epilogue: col<17408 -> gates [chain][t][272] bf16; else vvT [chain][t][16] f32.
// ---------------------------------------------------------------------------
__global__ __launch_bounds__(512) void gemm256_gates(
    const u16* __restrict__ A, const u16* __restrict__ Bt,
    u16* __restrict__ gates, float* __restrict__ vvT)
{
    constexpr int K = 1024;
    constexpr int NTILE = 16;                    // K / 64

    // bijective XCD swizzle: 576 blocks, 72 per XCD = 9 bx x 8 by, by innermost
    int f = blockIdx.y * gridDim.x + blockIdx.x;
    int xcd = f & 7, k = f >> 3;                 // k in [0,72)
    const int by = k & 7;
    const int bx = xcd * 9 + (k >> 3);
    const int m0 = by * 256;
    const int n0 = bx * 256;
    (void)n0;

    __shared__ alignas(16) u16 sA[2][2][8192];   // [buf][khalf][256*32]
    __shared__ alignas(16) u16 sB[2][2][8192];

    const int tid  = threadIdx.x;                // 0..511
    const int lane = tid & 63, w = tid >> 6;     // 8 waves
    const int wr = w >> 2, wc = w & 3;           // 2 x 4 wave grid
    const int quad = lane >> 4, l16 = lane & 15;
    const int f2l = (l16 & 3) ^ ((l16 >> 2) & 3);
    const int sq  = quad ^ f2l;                  // swizzled 16B slot for reads

    // staging sources (per-thread, inverse-swizzled global address; rule 21)
    const u16* srcA[2];
    const u16* srcB[2];
    int ldofs[2];
    #pragma unroll
    for (int it = 0; it < 2; ++it) {
        int sp = it * 512 + tid;                 // physical 16B slot in piece
        int r  = sp >> 2;                        // row 0..255
        int sl = (sp & 3) ^ ((r & 3) ^ ((r >> 2) & 3));  // logical slot
        srcA[it] = A  + (size_t)(m0 + r) * K + sl * 8;
        srcB[it] = Bt + (size_t)(n0 + r) * K + sl * 8;
        ldofs[it] = (it * 512 + (tid & ~63)) * 8;        // wave-uniform dest
    }

    // LDS read bases (u16 element offsets within a piece)
    const int aoff = (wr * 128 + l16) * 32 + sq * 8;
    const int boff = (wc * 64  + l16) * 32 + sq * 8;

    f32x4 acc[2][4][4] = {};                     // [om][mt][nt]

#define STG(piece, srcArr, ko)                                     \
    { stage16(srcArr[0] + (ko), &(piece)[ldofs[0]]);               \
      stage16(srcArr[1] + (ko), &(piece)[ldofs[1]]); }

#define MFMA_BLK(OM)                                               \
    __builtin_amdgcn_s_setprio(1);                                 \
    { _Pragma("unroll") for (int mt = 0; mt < 4; ++mt) {           \
        _Pragma("unroll") for (int nt = 0; nt < 4; ++nt)           \
          acc[OM][mt][nt] = __builtin_amdgcn_mfma_f32_16x16x32_bf16(\
              af[mt], bfr[nt], acc[OM][mt][nt], 0, 0, 0); } }      \
    __builtin_amdgcn_s_setprio(0);

    // prologue: stage tile 0 (order A0, B0, A1, B1 = steady-state order)
    STG(sA[0][0], srcA, 0);  STG(sB[0][0], srcB, 0);
    STG(sA[0][1], srcA, 32); STG(sB[0][1], srcB, 32);

    for (int t = 0; t < NTILE; ++t) {
        const int cur = t & 1, nxt = cur ^ 1;
        const int kn = (t < NTILE - 1 ? t + 1 : t) * 64;   // clamp: last iter restages in-bounds
        const u16* Ap0 = sA[cur][0];
        const u16* Bp0 = sB[cur][0];
        const u16* Ap1 = sA[cur][1];
        const u16* Bp1 = sB[cur][1];
        bf16x8 af[4], bfr[4];

        // W1: oldest 4 loads (A0,B0 of tile t) landed; 4 stay in flight.
        asm volatile("s_waitcnt vmcnt(4)\n\ts_barrier" ::: "memory");

        // ---- phase 1: kh0, om0
        #pragma unroll
        for (int nt = 0; nt < 4; ++nt) bfr[nt] = *(const bf16x8*)&Bp0[boff + nt * 512];
        #pragma unroll
        for (int mt = 0; mt < 4; ++mt) af[mt]  = *(const bf16x8*)&Ap0[aoff + mt * 512];
        STG(sA[nxt][0], srcA, kn);
        MFMA_BLK(0)

        // ---- phase 2: kh0, om1 (reuse bfr)
        #pragma unroll
        for (int mt = 0; mt < 4; ++mt) af[mt]  = *(const bf16x8*)&Ap0[aoff + 2048 + mt * 512];
        STG(sB[nxt][0], srcB, kn);
        MFMA_BLK(1)

        // W2: oldest 4 loads (A1,B1 of tile t) landed; 4 stay in flight.
        asm volatile("s_waitcnt vmcnt(4)\n\ts_barrier" ::: "memory");

        // ---- phase 3: kh1, om0
        #pragma unroll
        for (int nt = 0; nt < 4; ++nt) bfr[nt] = *(const bf16x8*)&Bp1[boff + nt * 512];
        #pragma unroll
        for (int mt = 0; mt < 4; ++mt) af[mt]  = *(const bf16x8*)&Ap1[aoff + mt * 512];
        STG(sA[nxt][1], srcA, kn + 32);
        MFMA_BLK(0)

        // ---- phase 4: kh1, om1 (reuse bfr)
        #pragma unroll
        for (int mt = 0; mt < 4; ++mt) af[mt]  = *(const bf16x8*)&Ap1[aoff + 2048 + mt * 512];
        STG(sB[nxt][1], srcB, kn + 32);
        MFMA_BLK(1)
    }
#undef STG
#undef MFMA_BLK

    // Epilogue: col = n0 + wc*64 + nt*16 + l16; row = m0 + wr*128 + om*64 + mt*16 + quad*4 + r
    const int cgbase = bx * 16 + wc * 4;
    #pragma unroll
    for (int om = 0; om < 2; ++om) {
        #pragma unroll
        for (int mt = 0; mt < 4; ++mt) {
            #pragma unroll
            for (int r = 0; r < 4; ++r) {
                int row = m0 + wr * 128 + om * 64 + mt * 16 + quad * 4 + r;
                int tt = row & (T_ - 1), bb = row >> 10;
                #pragma unroll
                for (int nt = 0; nt < 4; ++nt) {
                    int cg = cgbase + nt;                  // lane-uniform
                    float val = acc[om][mt][nt][r];
                    if (cg >= 1088) {
                        vvT[(((size_t)(bb * 64 + (cg - 1088))) * T_ + tt) * 16 + l16] = val;
                    } else {
                        int hh = cg / 17, rem = cg - hh * 17;
                        gates[(((size_t)(bb * 64 + hh)) * T_ + tt) * 272 + rem * 16 + l16] = f2b(val);
                    }
                }
            }
        }
    }
}

// ---------------------------------------------------------------------------
__global__ __launch_bounds__(256) void rmsnorm_k(
    const float* __restrict__ x, const float* __restrict__ w, u16* __restrict__ out)
{
    const int row = blockIdx.x, tid = threadIdx.x;
    float4 v = ((const float4*)(x + (size_t)row * D_))[tid];
    float ss = v.x * v.x + v.y * v.y + v.z * v.z + v.w * v.w;
    #pragma unroll
    for (int o = 32; o >= 1; o >>= 1) ss += __shfl_xor(ss, o, 64);
    __shared__ float red[4];
    if ((tid & 63) == 0) red[tid >> 6] = ss;
    __syncthreads();
    ss = red[0] + red[1] + red[2] + red[3];
    float scale = rsqrtf(ss * (1.0f / D_) + 1e-5f);
    float4 wv = ((const float4*)w)[tid];
    ushort4 o4;
    o4.x = f2b(v.x * scale * wv.x);
    o4.y = f2b(v.y * scale * wv.y);
    o4.z = f2b(v.z * scale * wv.z);
    o4.w = f2b(v.w * scale * wv.w);
    ((ushort4*)(out + (size_t)row * D_))[tid] = o4;
}

// ---------------------------------------------------------------------------
// All weight converts in one launch. Segments by blockIdx.x (all R=1024):
//   [0,96)   wqkv C=3072 -> wqkvT
//   [96,128) wao  C=1024 -> waoT
//   [128,160)wv   C=1024 -> waT + 17408*1024 (contiguous with waT)
//   [160,704)wa   C=17408-> waT
//   [704,736)wop  C=1024 -> wopT
// ---------------------------------------------------------------------------
__global__ void convT_all(
    const float* __restrict__ wqkv, const float* __restrict__ wao,
    const float* __restrict__ wv,   const float* __restrict__ wa,
    const float* __restrict__ wop,
    u16* __restrict__ wqkvT, u16* __restrict__ waoT,
    u16* __restrict__ waT,   u16* __restrict__ wopT)
{
    const int x = blockIdx.x;
    const float* in; u16* out; int C, xb;
    if (x < 96)       { in = wqkv; out = wqkvT; C = 3072;  xb = x; }
    else if (x < 128) { in = wao;  out = waoT;  C = 1024;  xb = x - 96; }
    else if (x < 160) { in = wv;   out = waT + (size_t)17408 * 1024; C = 1024; xb = x - 128; }
    else if (x < 704) { in = wa;   out = waT;   C = 17408; xb = x - 160; }
    else              { in = wop;  out = wopT;  C = 1024;  xb = x - 704; }
    constexpr int R = 1024;
    __shared__ float tile[32][33];
    const int c0 = xb * 32, r0 = blockIdx.y * 32;
    const int tx = threadIdx.x, ty = threadIdx.y;
    #pragma unroll
    for (int k = 0; k < 4; ++k)
        tile[ty + 8 * k][tx] = in[(size_t)(r0 + ty + 8 * k) * C + c0 + tx];
    __syncthreads();
    #pragma unroll
    for (int k = 0; k < 4; ++k)
        out[(size_t)(c0 + ty + 8 * k) * R + r0 + tx] = f2b(tile[tx][ty + 8 * k]);
}

__global__ void transpose_bf16_k(const u16* __restrict__ in_, u16* __restrict__ out_, int R, int C)
{
    __shared__ u16 tile[32][33];
    const u16* in = in_ + (size_t)blockIdx.z * R * C;
    u16* out      = out_ + (size_t)blockIdx.z * R * C;
    const int c0 = blockIdx.x * 32, r0 = blockIdx.y * 32;
    const int tx = threadIdx.x, ty = threadIdx.y;
    #pragma unroll
    for (int k = 0; k < 4; ++k)
        tile[ty + 8 * k][tx] = in[(size_t)(r0 + ty + 8 * k) * C + c0 + tx];
    __syncthreads();
    #pragma unroll
    for (int k = 0; k < 4; ++k)
        out[(size_t)(c0 + ty + 8 * k) * R + r0 + tx] = tile[tx][ty + 8 * k];
}

// ---------------------------------------------------------------------------
// Causal softmax, wave-per-row (4 rows/block). Only k < kmax = roundup(t+1,64)
// is read/written (PV's TRUNCK reads exactly that range).
// ---------------------------------------------------------------------------
__global__ __launch_bounds__(256) void softmax_causal_k(u16* __restrict__ S)
{
    const int w = threadIdx.x >> 6, lane = threadIdx.x & 63;
    const int z = blockIdx.x * 4 + w;
    const int t = z & (T_ - 1);
    u16* row = S + (size_t)z * T_;
    const int n = t + 1;
    const int kmax = (t & ~63) + 64;
    const int kb = lane * 4;
    float v[4][4];
    float mx = -1e30f;
    #pragma unroll
    for (int it = 0; it < 4; ++it) {
        int k = it * 256 + kb;
        if (k < kmax) {
            uint2 d = *(const uint2*)(row + k);
            v[it][0] = (k + 0 < n) ? blo(d.x) * 0.125f : -1e30f;
            v[it][1] = (k + 1 < n) ? bhi(d.x) * 0.125f : -1e30f;
            v[it][2] = (k + 2 < n) ? blo(d.y) * 0.125f : -1e30f;
            v[it][3] = (k + 3 < n) ? bhi(d.y) * 0.125f : -1e30f;
        } else {
            v[it][0] = v[it][1] = v[it][2] = v[it][3] = -1e30f;
        }
        mx = fmaxf(mx, fmaxf(fmaxf(v[it][0], v[it][1]), fmaxf(v[it][2], v[it][3])));
    }
    #pragma unroll
    for (int o = 32; o >= 1; o >>= 1) mx = fmaxf(mx, __shfl_xor(mx, o, 64));
    float sum = 0.f;
    #pragma unroll
    for (int it = 0; it < 4; ++it)
        #pragma unroll
        for (int j = 0; j < 4; ++j) {
            float e = (v[it][j] > -1e29f) ? __expf(v[it][j] - mx) : 0.f;
            v[it][j] = e;
            sum += e;
        }
    #pragma unroll
    for (int o = 32; o >= 1; o >>= 1) sum += __shfl_xor(sum, o, 64);
    float inv = 1.0f / sum;
    #pragma unroll
    for (int it = 0; it < 4; ++it) {
        int k = it * 256 + kb;
        if (k < kmax) {
            uint2 d;
            d.x = (u32)f2b(v[it][0] * inv) | ((u32)f2b(v[it][1] * inv) << 16);
            d.y = (u32)f2b(v[it][2] * inv) | ((u32)f2b(v[it][3] * inv) << 16);
            *(uint2*)(row + k) = d;
        }
    }
}

// ---------------------------------------------------------------------------
// Scan-chunk prep (shared by p1/p2): raw gate logits for a 32-step chunk in
// glds (32 x 16 rows x 17 bf16 @ 34 B). Softmax each row, repack the 16
// A-entries in place to (st*16+i)*32 B (bf16), scale vlds (v -> a0*v).
// ---------------------------------------------------------------------------
__device__ __forceinline__ void scan_prep(u16* glds, float* vlds, int lane)
{
    #pragma unroll
    for (int rnd = 0; rnd < 2; ++rnd) {
        float p[4][17];
        #pragma unroll
        for (int j = 0; j < 4; ++j) {
            int r = rnd * 256 + j * 64 + lane;
            const u16* g = &glds[r * 17];
            float vv[17];
            float mx = -1e30f;
            #pragma unroll
            for (int tt = 0; tt < 17; ++tt) { vv[tt] = b2f(g[tt]); mx = fmaxf(mx, vv[tt]); }
            float s = 0.f;
            #pragma unroll
            for (int tt = 0; tt < 17; ++tt) { vv[tt] = __expf(vv[tt] - mx); s += vv[tt]; }
            float inv = 1.0f / s;
            #pragma unroll
            for (int tt = 0; tt < 17; ++tt) p[j][tt] = vv[tt] * inv;
        }
        __syncthreads();
        #pragma unroll
        for (int j = 0; j < 4; ++j) {
            int r = rnd * 256 + j * 64 + lane;
            uint4 w0, w1;
            w0.x = (u32)f2b(p[j][1])  | ((u32)f2b(p[j][2])  << 16);
            w0.y = (u32)f2b(p[j][3])  | ((u32)f2b(p[j][4])  << 16);
            w0.z = (u32)f2b(p[j][5])  | ((u32)f2b(p[j][6])  << 16);
            w0.w = (u32)f2b(p[j][7])  | ((u32)f2b(p[j][8])  << 16);
            w1.x = (u32)f2b(p[j][9])  | ((u32)f2b(p[j][10]) << 16);
            w1.y = (u32)f2b(p[j][11]) | ((u32)f2b(p[j][12]) << 16);
            w1.z = (u32)f2b(p[j][13]) | ((u32)f2b(p[j][14]) << 16);
            w1.w = (u32)f2b(p[j][15]) | ((u32)f2b(p[j][16]) << 16);
            ((uint4*)glds)[r * 2]     = w0;
            ((uint4*)glds)[r * 2 + 1] = w1;
            vlds[r] *= p[j][0];
        }
        __syncthreads();
    }
}

// ---------------------------------------------------------------------------
// scan pass 1: per chunk of 32 steps compute P_c = A_31..A_0, e_c.
// ---------------------------------------------------------------------------
__global__ __launch_bounds__(64) void scan_p1(
    const u16* __restrict__ gates, const float* __restrict__ vvT,
    float* __restrict__ Pmat, float* __restrict__ evec)
{
    const int c = blockIdx.x, chain = blockIdx.y;
    const int lane = threadIdx.x;
    const int i = lane >> 2, q = lane & 3;
    __shared__ alignas(16) u16   glds[32 * 272];
    __shared__ alignas(16) float vlds[32 * 16];
    __shared__ alignas(16) float Pb[2][256];
    __shared__ float slds[16];

    const char* gbase = (const char*)(gates + ((size_t)chain * T_ + c * 32) * 272);
    #pragma unroll
    for (int it = 0; it < 17; ++it)
        stage16(gbase + it * 1024 + lane * 16, (char*)glds + it * 1024);
    const char* vbase = (const char*)(vvT + ((size_t)chain * T_ + c * 32) * 16);
    #pragma unroll
    for (int it = 0; it < 2; ++it)
        stage16(vbase + it * 1024 + lane * 16, (char*)vlds + it * 1024);
    __syncthreads();

    scan_prep(glds, vlds, lane);

    {
        f32x4 idq;
        #pragma unroll
        for (int m = 0; m < 4; ++m) idq[m] = (i == q * 4 + m) ? 1.f : 0.f;
        *(f32x4*)&Pb[0][i * 16 + q * 4] = idq;
    }
    f32x4 e4[4] = {};
    f32x4 np = {};
    float neLast = 0.f;
    int cur = 0;

    for (int st = 0; st < 32; ++st) {
        const uint4* rp = (const uint4*)((const char*)glds + (st * 16 + i) * 32);
        uint4 d0 = rp[0], d1 = rp[1];
        float ar[16];
        ar[0]  = blo(d0.x); ar[1]  = bhi(d0.x);
        ar[2]  = blo(d0.y); ar[3]  = bhi(d0.y);
        ar[4]  = blo(d0.z); ar[5]  = bhi(d0.z);
        ar[6]  = blo(d0.w); ar[7]  = bhi(d0.w);
        ar[8]  = blo(d1.x); ar[9]  = bhi(d1.x);
        ar[10] = blo(d1.y); ar[11] = bhi(d1.y);
        ar[12] = blo(d1.z); ar[13] = bhi(d1.z);
        ar[14] = blo(d1.w); ar[15] = bhi(d1.w);

        f32x4 pk[16];
        #pragma unroll
        for (int k = 0; k < 16; ++k)
            pk[k] = *(const f32x4*)&Pb[cur][k * 16 + q * 4];

        f32x4 a = pk[0] * ar[0];
        #pragma unroll
        for (int k = 1; k < 16; ++k) a += pk[k] * ar[k];
        np = a;

        float ne0 = ar[0] * e4[0][0] + ar[1] * e4[0][1] + ar[2] * e4[0][2] + ar[3] * e4[0][3];
        float ne1 = ar[4] * e4[1][0] + ar[5] * e4[1][1] + ar[6] * e4[1][2] + ar[7] * e4[1][3];
        float ne2 = ar[8] * e4[2][0] + ar[9] * e4[2][1] + ar[10] * e4[2][2] + ar[11] * e4[2][3];
        float ne3 = ar[12] * e4[3][0] + ar[13] * e4[3][1] + ar[14] * e4[3][2] + ar[15] * e4[3][3];
        float ne = (ne0 + ne1) + (ne2 + ne3) + vlds[st * 16 + i];

        *(f32x4*)&Pb[cur ^ 1][i * 16 + q * 4] = np;
        if (q == 0) slds[i] = ne;
        #pragma unroll
        for (int m = 0; m < 4; ++m) e4[m] = *(const f32x4*)&slds[m * 4];
        neLast = ne;
        cur ^= 1;
    }

    float* Pd = Pmat + ((size_t)chain * 32 + c) * 256;
    *(f32x4*)&Pd[i * 16 + q * 4] = np;
    if (q == 0) evec[((size_t)chain * 32 + c) * 16 + i] = neLast;
}

// ---------------------------------------------------------------------------
// scan pass 2: per chain, sequentially combine 32 chunks; sIn[c] = entry state.
// ---------------------------------------------------------------------------
__global__ __launch_bounds__(64) void scan_comb(
    const float* __restrict__ Pmat, const float* __restrict__ evec, float* __restrict__ sIn)
{
    const int chain = blockIdx.x;
    const int lane = threadIdx.x;
    const int i = lane >> 2, q = lane & 3;
    __shared__ alignas(16) float Pl[32 * 256];
    __shared__ alignas(16) float El[32 * 16];
    __shared__ float slds[16];

    const char* Pg = (const char*)(Pmat + (size_t)chain * 32 * 256);
    #pragma unroll
    for (int it = 0; it < 32; ++it)
        stage16(Pg + it * 1024 + lane * 16, (char*)Pl + it * 1024);
    const char* Eg = (const char*)(evec + (size_t)chain * 32 * 16);
    #pragma unroll
    for (int it = 0; it < 2; ++it)
        stage16(Eg + it * 1024 + lane * 16, (char*)El + it * 1024);
    __syncthreads();

    f32x4 s4[4] = {};
    if (q == 0) sIn[((size_t)chain * 32 + 0) * 16 + i] = 0.f;
    for (int cc = 0; cc < 32; ++cc) {
        f32x4 pr[4];
        #pragma unroll
        for (int m = 0; m < 4; ++m)
            pr[m] = *(const f32x4*)&Pl[cc * 256 + i * 16 + m * 4];
        float ne = 0.f;
        #pragma unroll
        for (int k = 0; k < 16; ++k) ne += pr[k >> 2][k & 3] * s4[k >> 2][k & 3];
        ne += El[cc * 16 + i];
        if (q == 0) {
            slds[i] = ne;
            if (cc < 31) sIn[((size_t)chain * 32 + cc + 1) * 16 + i] = ne;
        }
        #pragma unroll
        for (int m = 0; m < 4; ++m) s4[m] = *(const f32x4*)&slds[m * 4];
    }
}

// ---------------------------------------------------------------------------
// scan pass 3: replay each chunk from its entry state, write h_out.
// ---------------------------------------------------------------------------
__global__ __launch_bounds__(64) void scan_p2(
    const u16* __restrict__ gates, const float* __restrict__ vvT,
    const float* __restrict__ sIn, u16* __restrict__ hout)
{
    const int c = blockIdx.x, chain = blockIdx.y;
    const int b = chain >> 6, hh = chain & 63;
    const int lane = threadIdx.x;
    const int i = lane >> 2, q = lane & 3;
    __shared__ alignas(16) u16   glds[32 * 272];
    __shared__ alignas(16) float vlds[32 * 16];
    __shared__ float slds[16];

    const char* gbase = (const char*)(gates + ((size_t)chain * T_ + c * 32) * 272);
    #pragma unroll
    for (int it = 0; it < 17; ++it)
        stage16(gbase + it * 1024 + lane * 16, (char*)glds + it * 1024);
    const char* vbase = (const char*)(vvT + ((size_t)chain * T_ + c * 32) * 16);
    #pragma unroll
    for (int it = 0; it < 2; ++it)
        stage16(vbase + it * 1024 + lane * 16, (char*)vlds + it * 1024);
    __syncthreads();

    scan_prep(glds, vlds, lane);

    const float* sp = sIn + ((size_t)chain * 32 + c) * 16;
    f32x4 s4[4];
    #pragma unroll
    for (int m = 0; m < 4; ++m) s4[m] = *(const f32x4*)(sp + m * 4);

    u16* hbase = hout + ((size_t)(b * T_ + c * 32)) * D_ + hh * 16;
    for (int st = 0; st < 32; ++st) {
        const uint4* rp = (const uint4*)((const char*)glds + (st * 16 + i) * 32);
        uint4 d0 = rp[0], d1 = rp[1];
        float ne0 = blo(d0.x) * s4[0][0] + bhi(d0.x) * s4[0][1]
                  + blo(d0.y) * s4[0][2] + bhi(d0.y) * s4[0][3];
        float ne1 = blo(d0.z) * s4[1][0] + bhi(d0.z) * s4[1][1]
                  + blo(d0.w) * s4[1][2] + bhi(d0.w) * s4[1][3];
        float ne2 = blo(d1.x) * s4[2][0] + bhi(d1.x) * s4[2][1]
                  + blo(d1.y) * s4[2][2] + bhi(d1.y) * s4[2][3];
        float ne3 = blo(d1.z) * s4[3][0] + bhi(d1.z) * s4[3][1]
                  + blo(d1.w) * s4[3][2] + bhi(d1.w) * s4[3][3];
        float ne = (ne0 + ne1) + (ne2 + ne3) + vlds[st * 16 + i];
        if (q == 0) {
            slds[i] = ne;
            hbase[(size_t)st * D_ + i] = f2b(ne);
        }
        #pragma unroll
        for (int m = 0; m < 4; ++m) s4[m] = *(const f32x4*)&slds[m * 4];
    }
}

// ---------------------------------------------------------------------------
extern "C" void kernel_launch(void* const* d_in, const int* in_sizes, int n_in,
                              void* d_out, int out_size, void* d_ws, size_t ws_size,
                              hipStream_t stream)
{
    const float* x    = (const float*)d_in[0];
    const float* anw  = (const float*)d_in[1];
    const float* wqkv = (const float*)d_in[2];
    const float* wao  = (const float*)d_in[3];
    const float* lnw  = (const float*)d_in[4];
    const float* wv   = (const float*)d_in[5];
    const float* wa   = (const float*)d_in[6];
    const float* wop  = (const float*)d_in[7];

    char* ws = (char*)d_ws;
    const size_t MB = 1u << 20;
    u16*   h     = (u16*)  (ws +   0 * MB);   //  4 MB
    u16*   h2    = (u16*)  (ws +   4 * MB);   //  4 MB
    u16*   wqkvT = (u16*)  (ws +   8 * MB);   //  6 MB
    u16*   waoT  = (u16*)  (ws +  14 * MB);   //  2 MB
    u16*   wopT  = (u16*)  (ws +  16 * MB);   //  2 MB
    u16*   waT   = (u16*)  (ws +  18 * MB);   // 36 MB (wa 17408 rows + wv 1024 rows)
    float* x2    = (float*)(ws +  54 * MB);   //  8 MB
    float* vvT   = (float*)(ws +  62 * MB);   //  8 MB scan layout [chain][t][16]
    u16*   Qb    = (u16*)  (ws +  78 * MB);   //  4 MB (dead after QK^T)
    float* Pmat  = (float*)(ws +  78 * MB);   //  4 MB aliases Qb
    u16*   Kb    = (u16*)  (ws +  82 * MB);   //  4 MB (dead after QK^T)
    float* evec  = (float*)(ws +  82 * MB);   // 256 KB aliases Kb
    float* sIn   = (float*)(ws +  82 * MB + 256 * 1024); // 256 KB
    u16*   Vb    = (u16*)  (ws +  86 * MB);   //  4 MB (dead after transpose)
    u16*   Vt    = (u16*)  (ws +  90 * MB);   //  4 MB (dead after PV)
    u16*   S     = (u16*)  (ws +  94 * MB);   // 64 MB (dead after PV)
    u16*   omat  = (u16*)  (ws + 158 * MB);   //  4 MB (dead after attn_out)
    u16*   gates = (u16*)  (ws +  94 * MB);   // 68 MB aliases S+omat
    u16*   hout  = (u16*)  (ws + 162 * MB);   //  4 MB (end: 166 MB)
    (void)in_sizes; (void)n_in; (void)out_size; (void)ws_size;

    dim3 tb(32, 8);
    convT_all<<<dim3(736, 32), tb, 0, stream>>>(
        wqkv, wao, wv, wa, wop, wqkvT, waoT, waT, wopT);

    rmsnorm_k<<<2048, 256, 0, stream>>>(x, anw, h);
    // qkv GEMM with fused RoPE epilogue -> Qb, Kb, Vb directly
    gemm_bt<64, 128, 32, 6, false, false, 0><<<dim3(24, 32, 1), 256, 0, stream>>>(
        h, wqkvT, (void*)Qb, (void*)Kb, (void*)Vb, nullptr, 2048, 3072, 1024, 0, 0, 0);
    transpose_bf16_k<<<dim3(2, 32, 32), tb, 0, stream>>>(Vb, Vt, 1024, 64);

    // QK^T: K=64 -> BK=64, single staging round per block
    gemm_bt<128, 128, 64, 1, false, true, 0><<<dim3(8, 8, 32), 256, 0, stream>>>(
        Qb, Kb, (void*)S, nullptr, nullptr, nullptr, 1024, 1024, 64, 65536, 65536, 1048576);
    softmax_causal_k<<<8192, 256, 0, stream>>>(S);
    // PV: BM=64, BK=64
    gemm_bt<64, 64, 64, 2, true, false, 0><<<dim3(1, 16, 32), 256, 0, stream>>>(
        S, Vt, (void*)omat, nullptr, nullptr, nullptr, 1024, 64, 1024, 1048576, 65536, 0);

    gemm_bt<64, 128, 32, 0, false, false, 0><<<dim3(8, 32, 1), 256, 0, stream>>>(
        omat, waoT, (void*)x2, nullptr, nullptr, x, 2048, 1024, 1024, 0, 0, 0);
    rmsnorm_k<<<2048, 256, 0, stream>>>(x2, lnw, h2);

    // fused gates + w_v GEMM: 256x256 counted-vmcnt schedule, 576 blocks
    gemm256_gates<<<dim3(72, 8), 512, 0, stream>>>(h2, waT, gates, vvT);

    scan_p1<<<dim3(32, 128), 64, 0, stream>>>(gates, vvT, Pmat, evec);
    scan_comb<<<128, 64, 0, stream>>>(Pmat, evec, sIn);
    scan_p2<<<dim3(32, 128), 64, 0, stream>>>(gates, vvT, sIn, hout);

    gemm_bt<64, 128, 32, 0, false, false, 0><<<dim3(8, 32, 1), 256, 0, stream>>>(
        hout, wopT, d_out, nullptr, nullptr, x2, 2048, 1024, 1024, 0, 0, 0);
}

// Round 2
// 481.112 us; speedup vs baseline: 1.0643x; 1.0643x over previous
//
#include <hip/hip_runtime.h>

// HKSABlock on MI355X (gfx950). Round 9: gates GEMM re-done as 256x192,
// grid 96x8 = 768 blocks = EXACTLY 3 rounds at 1 block/CU (R8's 576-block
// grid lost 25% to the 2.25-round tail). Schedule is the m201-faithful
// 4-phase/K-tile skeleton: per phase {ds_read subtile || stage piece issue;
// s_barrier; lgkmcnt(0); setprio(1); 12 MFMA; setprio(0); s_barrier}, with
// counted vmcnt only at phase-1 end (vmcnt(3)) and phase-4 end (vmcnt(2)) --
// never 0 in the loop; piece issue order [B0,B1,B2|A0,A2|A1,A3] makes the
// oldest-prefix exactly the pieces the next phase reads. LDS rows are 64
// cols (128 B stride): XOR slot-swizzle phys=logical^(row&7), applied as
// inverse-swizzled global source + swizzled read (both-sides, rule 21).
// Everything else (qkv+RoPE GEMM, attention, scan) unchanged from R7.
// B=2, T=1024, D=1024, NH=16, HD=64, H=64, M=16.

typedef unsigned short u16;
typedef unsigned int   u32;
typedef __bf16 bf16x8 __attribute__((ext_vector_type(8)));
typedef float  f32x4  __attribute__((ext_vector_type(4)));

#define B_  2
#define T_  1024
#define D_  1024
#define NH_ 16
#define HD_ 64
#define H_  64
#define M_  16

__device__ __forceinline__ float b2f(u16 u) {
    return __uint_as_float(((u32)u) << 16);
}
__device__ __forceinline__ u16 f2b(float f) {
    u32 u = __float_as_uint(f);
    u32 r = (u + 0x7FFFu + ((u >> 16) & 1u)) >> 16;  // RNE
    return (u16)r;
}
__device__ __forceinline__ float blo(u32 u) { return __uint_as_float(u << 16); }
__device__ __forceinline__ float bhi(u32 u) { return __uint_as_float(u & 0xFFFF0000u); }

// Async global->LDS, 16 B per lane. LDS dest must be wave-uniform base.
__device__ __forceinline__ void stage16(const void* gp, void* lp) {
    typedef __attribute__((address_space(1))) const unsigned int GU;
    typedef __attribute__((address_space(3))) unsigned int LU;
    __builtin_amdgcn_global_load_lds((GU*)gp, (LU*)lp, 16, 0, 0);
}

// ---------------------------------------------------------------------------
// Generic MFMA GEMM: C[M,N] = A[M,K] * Bt[N,K]^T  (A,Bt bf16 row-major).
// 4 waves: wr = w>>1 (m-half), wc = w&1 (n-half). MT = BM/32, NT = BN/32.
// MODE 0: C fp32 (+ optional fp32 addend). MODE 1: C bf16.
// MODE 2: bf16 scatter into o_mat[(b*T + row)*1024 + h*64 + col], z = b*16+h.
// MODE 6: qkv + fused RoPE. N=3072; region = n0>>10 (0=Q,1=K,2=V). Each wave
//         owns one head's 64 cols; RoPE pair (i,i+32) = acc nt and nt+2.
//         Writes Qb(Cout)/Kb(Cout2)/Vb(Cout3) bf16 in (b,h,t,d).
// CAUSAL: skip blocks with n0 > m0+BM-1. TRUNCK: K truncated to m0+BM.
// ---------------------------------------------------------------------------
template<int BM, int BN, int BK, int MODE, bool TRUNCK, bool CAUSAL, int SWZ>
__global__ __launch_bounds__(256) void gemm_bt(
    const u16* __restrict__ A, const u16* __restrict__ Bt,
    void* __restrict__ Cout, void* __restrict__ Cout2, void* __restrict__ Cout3,
    const float* __restrict__ addend,
    int M, int N, int K, long strideA, long strideB, long strideC)
{
    constexpr int MT = BM / 32;
    constexpr int NT = BN / 32;
    constexpr int KCH = BK / 8;                  // 16B slots per row
    const int z  = blockIdx.z;
    int bx = blockIdx.x, by = blockIdx.y;
    if (SWZ == 2) {
        int f = by * gridDim.x + bx;
        int xcd = f & 7, k = f >> 3;
        by = k & 15;                             // by innermost per XCD
        bx = xcd * (gridDim.x >> 3) + (k >> 4);  // band per XCD
    }
    const int m0 = by * BM;
    const int n0 = bx * BN;
    if (CAUSAL && n0 > m0 + BM - 1) return;
    const int Keff = TRUNCK ? (K < m0 + BM ? K : m0 + BM) : K;

    const u16* Ab = A  + (size_t)z * (size_t)strideA;
    const u16* Bb = Bt + (size_t)z * (size_t)strideB;

    __shared__ alignas(16) u16 As[BM * BK];
    __shared__ alignas(16) u16 Bs[BN * BK];

    const int tid  = threadIdx.x;
    const int lane = tid & 63, w = tid >> 6;
    const int wr = w >> 1, wc = w & 1;
    const int quad = lane >> 4, l16 = lane & 15;

    f32x4 acc[MT][NT] = {};

    constexpr int AITER = (BM * BK / 8) / 256;
    constexpr int BITER = (BN * BK / 8) / 256;

    for (int k0 = 0; k0 < Keff; k0 += BK) {
        #pragma unroll
        for (int it = 0; it < AITER; ++it) {
            int c = it * 256 + tid;
            int m = c / KCH, kc = c % KCH;
            stage16(Ab + (size_t)(m0 + m) * K + k0 + kc * 8,
                    &As[(it * 256 + w * 64) * 8]);
        }
        #pragma unroll
        for (int it = 0; it < BITER; ++it) {
            int c = it * 256 + tid;
            int n = c / KCH, kc = c % KCH;
            stage16(Bb + (size_t)(n0 + n) * K + k0 + kc * 8,
                    &Bs[(it * 256 + w * 64) * 8]);
        }
        __syncthreads();

        #pragma unroll
        for (int kk = 0; kk < BK; kk += 32) {
            bf16x8 af[MT], bfr[NT];
            #pragma unroll
            for (int mt = 0; mt < MT; ++mt)
                af[mt] = *(const bf16x8*)&As[(wr * (BM / 2) + mt * 16 + l16) * BK + kk + quad * 8];
            #pragma unroll
            for (int nt = 0; nt < NT; ++nt)
                bfr[nt] = *(const bf16x8*)&Bs[(wc * (BN / 2) + nt * 16 + l16) * BK + kk + quad * 8];
            #pragma unroll
            for (int mt = 0; mt < MT; ++mt)
                #pragma unroll
                for (int nt = 0; nt < NT; ++nt)
                    acc[mt][nt] = __builtin_amdgcn_mfma_f32_16x16x32_bf16(
                        af[mt], bfr[nt], acc[mt][nt], 0, 0, 0);
        }
        __syncthreads();
    }

    // Epilogue. C/D layout: col = lane&15, row = (lane>>4)*4 + reg  [m89]
    if (MODE == 6) {
        // dedicated RoPE epilogue (NT==4, BN==128 required)
        const int reg = n0 >> 10;                      // 0=Q, 1=K, 2=V
        const int hh  = ((n0 & 1023) >> 6) + wc;       // head
        #pragma unroll
        for (int mt = 0; mt < MT; ++mt) {
            #pragma unroll
            for (int r = 0; r < 4; ++r) {
                int row = m0 + wr * (BM / 2) + mt * 16 + quad * 4 + r;
                int t = row & (T_ - 1), bb = row >> 10;
                size_t obase = ((size_t)(bb * NH_ + hh) * T_ + t) * HD_;
                if (reg == 2) {
                    #pragma unroll
                    for (int nt = 0; nt < 4; ++nt)
                        ((u16*)Cout3)[obase + nt * 16 + l16] = f2b(acc[mt][nt][r]);
                } else {
                    u16* dst = (reg == 0) ? (u16*)Cout : (u16*)Cout2;
                    #pragma unroll
                    for (int nt = 0; nt < 2; ++nt) {
                        int i = nt * 16 + l16;
                        float ang = (float)t * exp2f(-(float)i * 0.41524101186092034f);
                        float sn, cs;
                        sincosf(ang, &sn, &cs);
                        float q1 = acc[mt][nt][r], q2 = acc[mt][nt + 2][r];
                        dst[obase + i]      = f2b(q1 * cs - q2 * sn);
                        dst[obase + i + 32] = f2b(q2 * cs + q1 * sn);
                    }
                }
            }
        }
        return;
    }
    #pragma unroll
    for (int mt = 0; mt < MT; ++mt) {
        #pragma unroll
        for (int nt = 0; nt < NT; ++nt) {
            #pragma unroll
            for (int r = 0; r < 4; ++r) {
                int row = m0 + wr * (BM / 2) + mt * 16 + quad * 4 + r;
                int col = n0 + wc * (BN / 2) + nt * 16 + l16;
                float val = acc[mt][nt][r];
                if (MODE == 0) {
                    if (addend) val += addend[(size_t)row * N + col];
                    ((float*)Cout)[(size_t)z * (size_t)strideC + (size_t)row * N + col] = val;
                } else if (MODE == 1) {
                    ((u16*)Cout)[(size_t)z * (size_t)strideC + (size_t)row * N + col] = f2b(val);
                } else if (MODE == 2) {
                    size_t idx = ((size_t)(z >> 4) * T_ + row) * (size_t)D_ + (z & 15) * HD_ + col;
                    ((u16*)Cout)[idx] = f2b(val);
                }
            }
        }
    }
}

// ---------------------------------------------------------------------------
// gates+w_v GEMM: C[2048,18432] = h2[2048,1024] x waT[18432,1024]^T.
// 256x192 tile, grid 96x8 = 768 blocks = exactly 3 rounds of 256 CUs.
// 8 waves (wr=w>>2 in {0,1}, wc=w&3 in {0..3}), wave tile 128x48.
// LDS: sA[2][256*64] (64 KB) + sB[2][192*64] (48 KB) = 112 KB -> 1 block/CU.
// K-tile BK=64, staged as 7 pieces of 8 KB (64 rows x 64 cols), issue order
// [B0,B1,B2 | A0,A2 | A1,A3] across phases 1-3; vmcnt(3)@ph1-end covers
// A1,A3 (read by ph2/ph4), vmcnt(2)@ph4-end covers B*,A0,A2 (read by
// ph1/ph3 of next tile). Swizzle: 16B slot phys = logical ^ (row&7);
// write side via inverse-swizzled global source, read side per-lane const.
// Epilogue: cg<1088 -> gates [chain][t][272] bf16; else vvT fp32.
// ---------------------------------------------------------------------------
__global__ __launch_bounds__(512, 2) void gemm256_gates(
    const u16* __restrict__ A, const u16* __restrict__ Bt,
    u16* __restrict__ gates, float* __restrict__ vvT)
{
    constexpr int K = 1024;
    constexpr int NTILE = 16;                    // K / 64

    // bijective XCD swizzle: 768 blocks, 96 per XCD = 12 bx x 8 by, by innermost
    const int f = blockIdx.y * gridDim.x + blockIdx.x;
    const int xcd = f & 7, k = f >> 3;           // k in [0,96)
    const int by = k & 7;
    const int bx = xcd * 12 + (k >> 3);
    const int m0 = by * 256;
    const int n0 = bx * 192;

    __shared__ alignas(16) u16 sA[2][256 * 64];  // 64 KB
    __shared__ alignas(16) u16 sB[2][192 * 64];  // 48 KB

    const int tid  = threadIdx.x;                // 0..511
    const int lane = tid & 63, w = tid >> 6;     // 8 waves
    const int wr = w >> 2, wc = w & 3;           // 2 x 4 wave grid
    const int quad = lane >> 4, l16 = lane & 15;

    // staging: thread t handles row (t>>3) of each 64-row piece, physical
    // 16B slot (t&7); global source slot = (t&7) ^ (row&7)  (involution).
    const int colOff = (((tid & 7) ^ ((tid >> 3) & 7)) * 8);
    const u16* pA = A  + (size_t)(m0 + (tid >> 3)) * K + colOff;
    const u16* pB = Bt + (size_t)(n0 + (tid >> 3)) * K + colOff;
    const int wbase = (tid >> 6) * 512;          // wave-uniform LDS dest (u16)

    // ds-read bases (u16): row*64 + phys_slot*8; phys = (quad + 4*kh) ^ (l16&7)
    const int sq0 = quad ^ (l16 & 7);
    const int sq1 = sq0 ^ 4;
    const int aoff0 = (wr * 128 + l16) * 64 + sq0 * 8;
    const int aoff1 = (wr * 128 + l16) * 64 + sq1 * 8;
    const int boff0 = (wc * 48  + l16) * 64 + sq0 * 8;
    const int boff1 = (wc * 48  + l16) * 64 + sq1 * 8;

    f32x4 acc[2][4][3] = {};                     // [mh][mt][nt]

    u16* sAc = sA[0]; u16* sAn = sA[1];
    u16* sBc = sB[0]; u16* sBn = sB[1];

    // prologue: stage tile 0, order B0,B1,B2,A0,A2,A1,A3
    stage16(pB,                    sBc + wbase);
    stage16(pB + (size_t) 64 * K,  sBc +  4096 + wbase);
    stage16(pB + (size_t)128 * K,  sBc +  8192 + wbase);
    stage16(pA,                    sAc + wbase);
    stage16(pA + (size_t)128 * K,  sAc +  8192 + wbase);
    stage16(pA + (size_t) 64 * K,  sAc +  4096 + wbase);
    stage16(pA + (size_t)192 * K,  sAc + 12288 + wbase);
    asm volatile("s_waitcnt vmcnt(2)" ::: "memory");   // B*,A0,A2 landed
    __builtin_amdgcn_s_barrier();

    bf16x8 af[4], bfr[3];

#define MFMA12(MH)                                                   \
    __builtin_amdgcn_s_setprio(1);                                   \
    { _Pragma("unroll") for (int mt = 0; mt < 4; ++mt) {             \
        _Pragma("unroll") for (int nt = 0; nt < 3; ++nt)             \
          acc[MH][mt][nt] = __builtin_amdgcn_mfma_f32_16x16x32_bf16( \
              af[mt], bfr[nt], acc[MH][mt][nt], 0, 0, 0); } }        \
    __builtin_amdgcn_s_setprio(0);

    #pragma unroll 1
    for (int t = 0; t < NTILE; ++t) {
        const size_t kc = (size_t)((t < NTILE - 1 ? t + 1 : t) * 64); // next tile K
        // ---- phase 1: kh0, mh0;  stage B0,B1,B2 of next tile
        bfr[0] = *(const bf16x8*)&sBc[boff0];
        bfr[1] = *(const bf16x8*)&sBc[boff0 + 1024];
        bfr[2] = *(const bf16x8*)&sBc[boff0 + 2048];
        af[0]  = *(const bf16x8*)&sAc[aoff0];
        af[1]  = *(const bf16x8*)&sAc[aoff0 + 1024];
        af[2]  = *(const bf16x8*)&sAc[aoff0 + 2048];
        af[3]  = *(const bf16x8*)&sAc[aoff0 + 3072];
        stage16(pB + kc,                   sBn + wbase);
        stage16(pB + (size_t) 64 * K + kc, sBn + 4096 + wbase);
        stage16(pB + (size_t)128 * K + kc, sBn + 8192 + wbase);
        __builtin_amdgcn_s_barrier();
        asm volatile("s_waitcnt lgkmcnt(0)" ::: "memory");
        MFMA12(0)
        asm volatile("s_waitcnt vmcnt(3)" ::: "memory");   // A1,A3 of cur landed
        __builtin_amdgcn_s_barrier();

        // ---- phase 2: kh0, mh1;  stage A0,A2 of next tile
        af[0]  = *(const bf16x8*)&sAc[aoff0 + 4096];
        af[1]  = *(const bf16x8*)&sAc[aoff0 + 5120];
        af[2]  = *(const bf16x8*)&sAc[aoff0 + 6144];
        af[3]  = *(const bf16x8*)&sAc[aoff0 + 7168];
        stage16(pA + kc,                   sAn + wbase);
        stage16(pA + (size_t)128 * K + kc, sAn + 8192 + wbase);
        __builtin_amdgcn_s_barrier();
        asm volatile("s_waitcnt lgkmcnt(0)" ::: "memory");
        MFMA12(1)
        __builtin_amdgcn_s_barrier();

        // ---- phase 3: kh1, mh0;  stage A1,A3 of next tile
        bfr[0] = *(const bf16x8*)&sBc[boff1];
        bfr[1] = *(const bf16x8*)&sBc[boff1 + 1024];
        bfr[2] = *(const bf16x8*)&sBc[boff1 + 2048];
        af[0]  = *(const bf16x8*)&sAc[aoff1];
        af[1]  = *(const bf16x8*)&sAc[aoff1 + 1024];
        af[2]  = *(const bf16x8*)&sAc[aoff1 + 2048];
        af[3]  = *(const bf16x8*)&sAc[aoff1 + 3072];
        stage16(pA + (size_t) 64 * K + kc, sAn +  4096 + wbase);
        stage16(pA + (size_t)192 * K + kc, sAn + 12288 + wbase);
        __builtin_amdgcn_s_barrier();
        asm volatile("s_waitcnt lgkmcnt(0)" ::: "memory");
        MFMA12(0)
        __builtin_amdgcn_s_barrier();

        // ---- phase 4: kh1, mh1;  no staging
        af[0]  = *(const bf16x8*)&sAc[aoff1 + 4096];
        af[1]  = *(const bf16x8*)&sAc[aoff1 + 5120];
        af[2]  = *(const bf16x8*)&sAc[aoff1 + 6144];
        af[3]  = *(const bf16x8*)&sAc[aoff1 + 7168];
        __builtin_amdgcn_s_barrier();
        asm volatile("s_waitcnt lgkmcnt(0)" ::: "memory");
        MFMA12(1)
        asm volatile("s_waitcnt vmcnt(2)" ::: "memory");   // B*,A0,A2 of next landed
        __builtin_amdgcn_s_barrier();

        u16* tp;
        tp = sAc; sAc = sAn; sAn = tp;
        tp = sBc; sBc = sBn; sBn = tp;
    }
#undef MFMA12

    // Epilogue: row = m0 + wr*128 + mh*64 + mt*16 + quad*4 + r
    //           col-group cg = bx*12 + wc*3 + nt  (lane-uniform), col = cg*16+l16
    const int cgbase = bx * 12 + wc * 3;
    #pragma unroll
    for (int mh = 0; mh < 2; ++mh) {
        #pragma unroll
        for (int mt = 0; mt < 4; ++mt) {
            #pragma unroll
            for (int r = 0; r < 4; ++r) {
                int row = m0 + wr * 128 + mh * 64 + mt * 16 + quad * 4 + r;
                int tt = row & (T_ - 1), bb = row >> 10;
                #pragma unroll
                for (int nt = 0; nt < 3; ++nt) {
                    int cg = cgbase + nt;
                    float val = acc[mh][mt][nt][r];
                    if (cg >= 1088) {
                        vvT[(((size_t)(bb * 64 + (cg - 1088))) * T_ + tt) * 16 + l16] = val;
                    } else {
                        int hh = cg / 17, rem = cg - hh * 17;
                        gates[(((size_t)(bb * 64 + hh)) * T_ + tt) * 272 + rem * 16 + l16] = f2b(val);
                    }
                }
            }
        }
    }
}

// ---------------------------------------------------------------------------
__global__ __launch_bounds__(256) void rmsnorm_k(
    const float* __restrict__ x, const float* __restrict__ w, u16* __restrict__ out)
{
    const int row = blockIdx.x, tid = threadIdx.x;
    float4 v = ((const float4*)(x + (size_t)row * D_))[tid];
    float ss = v.x * v.x + v.y * v.y + v.z * v.z + v.w * v.w;
    #pragma unroll
    for (int o = 32; o >= 1; o >>= 1) ss += __shfl_xor(ss, o, 64);
    __shared__ float red[4];
    if ((tid & 63) == 0) red[tid >> 6] = ss;
    __syncthreads();
    ss = red[0] + red[1] + red[2] + red[3];
    float scale = rsqrtf(ss * (1.0f / D_) + 1e-5f);
    float4 wv = ((const float4*)w)[tid];
    ushort4 o4;
    o4.x = f2b(v.x * scale * wv.x);
    o4.y = f2b(v.y * scale * wv.y);
    o4.z = f2b(v.z * scale * wv.z);
    o4.w = f2b(v.w * scale * wv.w);
    ((ushort4*)(out + (size_t)row * D_))[tid] = o4;
}

// ---------------------------------------------------------------------------
// All weight converts in one launch. Segments by blockIdx.x (all R=1024):
//   [0,96)   wqkv C=3072 -> wqkvT
//   [96,128) wao  C=1024 -> waoT
//   [128,160)wv   C=1024 -> waT + 17408*1024 (contiguous with waT)
//   [160,704)wa   C=17408-> waT
//   [704,736)wop  C=1024 -> wopT
// ---------------------------------------------------------------------------
__global__ void convT_all(
    const float* __restrict__ wqkv, const float* __restrict__ wao,
    const float* __restrict__ wv,   const float* __restrict__ wa,
    const float* __restrict__ wop,
    u16* __restrict__ wqkvT, u16* __restrict__ waoT,
    u16* __restrict__ waT,   u16* __restrict__ wopT)
{
    const int x = blockIdx.x;
    const float* in; u16* out; int C, xb;
    if (x < 96)       { in = wqkv; out = wqkvT; C = 3072;  xb = x; }
    else if (x < 128) { in = wao;  out = waoT;  C = 1024;  xb = x - 96; }
    else if (x < 160) { in = wv;   out = waT + (size_t)17408 * 1024; C = 1024; xb = x - 128; }
    else if (x < 704) { in = wa;   out = waT;   C = 17408; xb = x - 160; }
    else              { in = wop;  out = wopT;  C = 1024;  xb = x - 704; }
    constexpr int R = 1024;
    __shared__ float tile[32][33];
    const int c0 = xb * 32, r0 = blockIdx.y * 32;
    const int tx = threadIdx.x, ty = threadIdx.y;
    #pragma unroll
    for (int k = 0; k < 4; ++k)
        tile[ty + 8 * k][tx] = in[(size_t)(r0 + ty + 8 * k) * C + c0 + tx];
    __syncthreads();
    #pragma unroll
    for (int k = 0; k < 4; ++k)
        out[(size_t)(c0 + ty + 8 * k) * R + r0 + tx] = f2b(tile[tx][ty + 8 * k]);
}

__global__ void transpose_bf16_k(const u16* __restrict__ in_, u16* __restrict__ out_, int R, int C)
{
    __shared__ u16 tile[32][33];
    const u16* in = in_ + (size_t)blockIdx.z * R * C;
    u16* out      = out_ + (size_t)blockIdx.z * R * C;
    const int c0 = blockIdx.x * 32, r0 = blockIdx.y * 32;
    const int tx = threadIdx.x, ty = threadIdx.y;
    #pragma unroll
    for (int k = 0; k < 4; ++k)
        tile[ty + 8 * k][tx] = in[(size_t)(r0 + ty + 8 * k) * C + c0 + tx];
    __syncthreads();
    #pragma unroll
    for (int k = 0; k < 4; ++k)
        out[(size_t)(c0 + ty + 8 * k) * R + r0 + tx] = tile[tx][ty + 8 * k];
}

// ---------------------------------------------------------------------------
// Causal softmax, wave-per-row (4 rows/block). Only k < kmax = roundup(t+1,64)
// is read/written (PV's TRUNCK reads exactly that range).
// ---------------------------------------------------------------------------
__global__ __launch_bounds__(256) void softmax_causal_k(u16* __restrict__ S)
{
    const int w = threadIdx.x >> 6, lane = threadIdx.x & 63;
    const int z = blockIdx.x * 4 + w;
    const int t = z & (T_ - 1);
    u16* row = S + (size_t)z * T_;
    const int n = t + 1;
    const int kmax = (t & ~63) + 64;
    const int kb = lane * 4;
    float v[4][4];
    float mx = -1e30f;
    #pragma unroll
    for (int it = 0; it < 4; ++it) {
        int k = it * 256 + kb;
        if (k < kmax) {
            uint2 d = *(const uint2*)(row + k);
            v[it][0] = (k + 0 < n) ? blo(d.x) * 0.125f : -1e30f;
            v[it][1] = (k + 1 < n) ? bhi(d.x) * 0.125f : -1e30f;
            v[it][2] = (k + 2 < n) ? blo(d.y) * 0.125f : -1e30f;
            v[it][3] = (k + 3 < n) ? bhi(d.y) * 0.125f : -1e30f;
        } else {
            v[it][0] = v[it][1] = v[it][2] = v[it][3] = -1e30f;
        }
        mx = fmaxf(mx, fmaxf(fmaxf(v[it][0], v[it][1]), fmaxf(v[it][2], v[it][3])));
    }
    #pragma unroll
    for (int o = 32; o >= 1; o >>= 1) mx = fmaxf(mx, __shfl_xor(mx, o, 64));
    float sum = 0.f;
    #pragma unroll
    for (int it = 0; it < 4; ++it)
        #pragma unroll
        for (int j = 0; j < 4; ++j) {
            float e = (v[it][j] > -1e29f) ? __expf(v[it][j] - mx) : 0.f;
            v[it][j] = e;
            sum += e;
        }
    #pragma unroll
    for (int o = 32; o >= 1; o >>= 1) sum += __shfl_xor(sum, o, 64);
    float inv = 1.0f / sum;
    #pragma unroll
    for (int it = 0; it < 4; ++it) {
        int k = it * 256 + kb;
        if (k < kmax) {
            uint2 d;
            d.x = (u32)f2b(v[it][0] * inv) | ((u32)f2b(v[it][1] * inv) << 16);
            d.y = (u32)f2b(v[it][2] * inv) | ((u32)f2b(v[it][3] * inv) << 16);
            *(uint2*)(row + k) = d;
        }
    }
}

// ---------------------------------------------------------------------------
// Scan-chunk prep (shared by p1/p2): raw gate logits for a 32-step chunk in
// glds (32 x 16 rows x 17 bf16 @ 34 B). Softmax each row, repack the 16
// A-entries in place to (st*16+i)*32 B (bf16), scale vlds (v -> a0*v).
// ---------------------------------------------------------------------------
__device__ __forceinline__ void scan_prep(u16* glds, float* vlds, int lane)
{
    #pragma unroll
    for (int rnd = 0; rnd < 2; ++rnd) {
        float p[4][17];
        #pragma unroll
        for (int j = 0; j < 4; ++j) {
            int r = rnd * 256 + j * 64 + lane;
            const u16* g = &glds[r * 17];
            float vv[17];
            float mx = -1e30f;
            #pragma unroll
            for (int tt = 0; tt < 17; ++tt) { vv[tt] = b2f(g[tt]); mx = fmaxf(mx, vv[tt]); }
            float s = 0.f;
            #pragma unroll
            for (int tt = 0; tt < 17; ++tt) { vv[tt] = __expf(vv[tt] - mx); s += vv[tt]; }
            float inv = 1.0f / s;
            #pragma unroll
            for (int tt = 0; tt < 17; ++tt) p[j][tt] = vv[tt] * inv;
        }
        __syncthreads();
        #pragma unroll
        for (int j = 0; j < 4; ++j) {
            int r = rnd * 256 + j * 64 + lane;
            uint4 w0, w1;
            w0.x = (u32)f2b(p[j][1])  | ((u32)f2b(p[j][2])  << 16);
            w0.y = (u32)f2b(p[j][3])  | ((u32)f2b(p[j][4])  << 16);
            w0.z = (u32)f2b(p[j][5])  | ((u32)f2b(p[j][6])  << 16);
            w0.w = (u32)f2b(p[j][7])  | ((u32)f2b(p[j][8])  << 16);
            w1.x = (u32)f2b(p[j][9])  | ((u32)f2b(p[j][10]) << 16);
            w1.y = (u32)f2b(p[j][11]) | ((u32)f2b(p[j][12]) << 16);
            w1.z = (u32)f2b(p[j][13]) | ((u32)f2b(p[j][14]) << 16);
            w1.w = (u32)f2b(p[j][15]) | ((u32)f2b(p[j][16]) << 16);
            ((uint4*)glds)[r * 2]     = w0;
            ((uint4*)glds)[r * 2 + 1] = w1;
            vlds[r] *= p[j][0];
        }
        __syncthreads();
    }
}

// ---------------------------------------------------------------------------
// scan pass 1: per chunk of 32 steps compute P_c = A_31..A_0, e_c.
// ---------------------------------------------------------------------------
__global__ __launch_bounds__(64) void scan_p1(
    const u16* __restrict__ gates, const float* __restrict__ vvT,
    float* __restrict__ Pmat, float* __restrict__ evec)
{
    const int c = blockIdx.x, chain = blockIdx.y;
    const int lane = threadIdx.x;
    const int i = lane >> 2, q = lane & 3;
    __shared__ alignas(16) u16   glds[32 * 272];
    __shared__ alignas(16) float vlds[32 * 16];
    __shared__ alignas(16) float Pb[2][256];
    __shared__ float slds[16];

    const char* gbase = (const char*)(gates + ((size_t)chain * T_ + c * 32) * 272);
    #pragma unroll
    for (int it = 0; it < 17; ++it)
        stage16(gbase + it * 1024 + lane * 16, (char*)glds + it * 1024);
    const char* vbase = (const char*)(vvT + ((size_t)chain * T_ + c * 32) * 16);
    #pragma unroll
    for (int it = 0; it < 2; ++it)
        stage16(vbase + it * 1024 + lane * 16, (char*)vlds + it * 1024);
    __syncthreads();

    scan_prep(glds, vlds, lane);

    {
        f32x4 idq;
        #pragma unroll
        for (int m = 0; m < 4; ++m) idq[m] = (i == q * 4 + m) ? 1.f : 0.f;
        *(f32x4*)&Pb[0][i * 16 + q * 4] = idq;
    }
    f32x4 e4[4] = {};
    f32x4 np = {};
    float neLast = 0.f;
    int cur = 0;

    for (int st = 0; st < 32; ++st) {
        const uint4* rp = (const uint4*)((const char*)glds + (st * 16 + i) * 32);
        uint4 d0 = rp[0], d1 = rp[1];
        float ar[16];
        ar[0]  = blo(d0.x); ar[1]  = bhi(d0.x);
        ar[2]  = blo(d0.y); ar[3]  = bhi(d0.y);
        ar[4]  = blo(d0.z); ar[5]  = bhi(d0.z);
        ar[6]  = blo(d0.w); ar[7]  = bhi(d0.w);
        ar[8]  = blo(d1.x); ar[9]  = bhi(d1.x);
        ar[10] = blo(d1.y); ar[11] = bhi(d1.y);
        ar[12] = blo(d1.z); ar[13] = bhi(d1.z);
        ar[14] = blo(d1.w); ar[15] = bhi(d1.w);

        f32x4 pk[16];
        #pragma unroll
        for (int k = 0; k < 16; ++k)
            pk[k] = *(const f32x4*)&Pb[cur][k * 16 + q * 4];

        f32x4 a = pk[0] * ar[0];
        #pragma unroll
        for (int k = 1; k < 16; ++k) a += pk[k] * ar[k];
        np = a;

        float ne0 = ar[0] * e4[0][0] + ar[1] * e4[0][1] + ar[2] * e4[0][2] + ar[3] * e4[0][3];
        float ne1 = ar[4] * e4[1][0] + ar[5] * e4[1][1] + ar[6] * e4[1][2] + ar[7] * e4[1][3];
        float ne2 = ar[8] * e4[2][0] + ar[9] * e4[2][1] + ar[10] * e4[2][2] + ar[11] * e4[2][3];
        float ne3 = ar[12] * e4[3][0] + ar[13] * e4[3][1] + ar[14] * e4[3][2] + ar[15] * e4[3][3];
        float ne = (ne0 + ne1) + (ne2 + ne3) + vlds[st * 16 + i];

        *(f32x4*)&Pb[cur ^ 1][i * 16 + q * 4] = np;
        if (q == 0) slds[i] = ne;
        #pragma unroll
        for (int m = 0; m < 4; ++m) e4[m] = *(const f32x4*)&slds[m * 4];
        neLast = ne;
        cur ^= 1;
    }

    float* Pd = Pmat + ((size_t)chain * 32 + c) * 256;
    *(f32x4*)&Pd[i * 16 + q * 4] = np;
    if (q == 0) evec[((size_t)chain * 32 + c) * 16 + i] = neLast;
}

// ---------------------------------------------------------------------------
// scan pass 2: per chain, sequentially combine 32 chunks; sIn[c] = entry state.
// ---------------------------------------------------------------------------
__global__ __launch_bounds__(64) void scan_comb(
    const float* __restrict__ Pmat, const float* __restrict__ evec, float* __restrict__ sIn)
{
    const int chain = blockIdx.x;
    const int lane = threadIdx.x;
    const int i = lane >> 2, q = lane & 3;
    __shared__ alignas(16) float Pl[32 * 256];
    __shared__ alignas(16) float El[32 * 16];
    __shared__ float slds[16];

    const char* Pg = (const char*)(Pmat + (size_t)chain * 32 * 256);
    #pragma unroll
    for (int it = 0; it < 32; ++it)
        stage16(Pg + it * 1024 + lane * 16, (char*)Pl + it * 1024);
    const char* Eg = (const char*)(evec + (size_t)chain * 32 * 16);
    #pragma unroll
    for (int it = 0; it < 2; ++it)
        stage16(Eg + it * 1024 + lane * 16, (char*)El + it * 1024);
    __syncthreads();

    f32x4 s4[4] = {};
    if (q == 0) sIn[((size_t)chain * 32 + 0) * 16 + i] = 0.f;
    for (int cc = 0; cc < 32; ++cc) {
        f32x4 pr[4];
        #pragma unroll
        for (int m = 0; m < 4; ++m)
            pr[m] = *(const f32x4*)&Pl[cc * 256 + i * 16 + m * 4];
        float ne = 0.f;
        #pragma unroll
        for (int k = 0; k < 16; ++k) ne += pr[k >> 2][k & 3] * s4[k >> 2][k & 3];
        ne += El[cc * 16 + i];
        if (q == 0) {
            slds[i] = ne;
            if (cc < 31) sIn[((size_t)chain * 32 + cc + 1) * 16 + i] = ne;
        }
        #pragma unroll
        for (int m = 0; m < 4; ++m) s4[m] = *(const f32x4*)&slds[m * 4];
    }
}

// ---------------------------------------------------------------------------
// scan pass 3: replay each chunk from its entry state, write h_out.
// ---------------------------------------------------------------------------
__global__ __launch_bounds__(64) void scan_p2(
    const u16* __restrict__ gates, const float* __restrict__ vvT,
    const float* __restrict__ sIn, u16* __restrict__ hout)
{
    const int c = blockIdx.x, chain = blockIdx.y;
    const int b = chain >> 6, hh = chain & 63;
    const int lane = threadIdx.x;
    const int i = lane >> 2, q = lane & 3;
    __shared__ alignas(16) u16   glds[32 * 272];
    __shared__ alignas(16) float vlds[32 * 16];
    __shared__ float slds[16];

    const char* gbase = (const char*)(gates + ((size_t)chain * T_ + c * 32) * 272);
    #pragma unroll
    for (int it = 0; it < 17; ++it)
        stage16(gbase + it * 1024 + lane * 16, (char*)glds + it * 1024);
    const char* vbase = (const char*)(vvT + ((size_t)chain * T_ + c * 32) * 16);
    #pragma unroll
    for (int it = 0; it < 2; ++it)
        stage16(vbase + it * 1024 + lane * 16, (char*)vlds + it * 1024);
    __syncthreads();

    scan_prep(glds, vlds, lane);

    const float* sp = sIn + ((size_t)chain * 32 + c) * 16;
    f32x4 s4[4];
    #pragma unroll
    for (int m = 0; m < 4; ++m) s4[m] = *(const f32x4*)(sp + m * 4);

    u16* hbase = hout + ((size_t)(b * T_ + c * 32)) * D_ + hh * 16;
    for (int st = 0; st < 32; ++st) {
        const uint4* rp = (const uint4*)((const char*)glds + (st * 16 + i) * 32);
        uint4 d0 = rp[0], d1 = rp[1];
        float ne0 = blo(d0.x) * s4[0][0] + bhi(d0.x) * s4[0][1]
                  + blo(d0.y) * s4[0][2] + bhi(d0.y) * s4[0][3];
        float ne1 = blo(d0.z) * s4[1][0] + bhi(d0.z) * s4[1][1]
                  + blo(d0.w) * s4[1][2] + bhi(d0.w) * s4[1][3];
        float ne2 = blo(d1.x) * s4[2][0] + bhi(d1.x) * s4[2][1]
                  + blo(d1.y) * s4[2][2] + bhi(d1.y) * s4[2][3];
        float ne3 = blo(d1.z) * s4[3][0] + bhi(d1.z) * s4[3][1]
                  + blo(d1.w) * s4[3][2] + bhi(d1.w) * s4[3][3];
        float ne = (ne0 + ne1) + (ne2 + ne3) + vlds[st * 16 + i];
        if (q == 0) {
            slds[i] = ne;
            hbase[(size_t)st * D_ + i] = f2b(ne);
        }
        #pragma unroll
        for (int m = 0; m < 4; ++m) s4[m] = *(const f32x4*)&slds[m * 4];
    }
}

// ---------------------------------------------------------------------------
extern "C" void kernel_launch(void* const* d_in, const int* in_sizes, int n_in,
                              void* d_out, int out_size, void* d_ws, size_t ws_size,
                              hipStream_t stream)
{
    const float* x    = (const float*)d_in[0];
    const float* anw  = (const float*)d_in[1];
    const float* wqkv = (const float*)d_in[2];
    const float* wao  = (const float*)d_in[3];
    const float* lnw  = (const float*)d_in[4];
    const float* wv   = (const float*)d_in[5];
    const float* wa   = (const float*)d_in[6];
    const float* wop  = (const float*)d_in[7];

    char* ws = (char*)d_ws;
    const size_t MB = 1u << 20;
    u16*   h     = (u16*)  (ws +   0 * MB);   //  4 MB
    u16*   h2    = (u16*)  (ws +   4 * MB);   //  4 MB
    u16*   wqkvT = (u16*)  (ws +   8 * MB);   //  6 MB
    u16*   waoT  = (u16*)  (ws +  14 * MB);   //  2 MB
    u16*   wopT  = (u16*)  (ws +  16 * MB);   //  2 MB
    u16*   waT   = (u16*)  (ws +  18 * MB);   // 36 MB (wa 17408 rows + wv 1024 rows)
    float* x2    = (float*)(ws +  54 * MB);   //  8 MB
    float* vvT   = (float*)(ws +  62 * MB);   //  8 MB scan layout [chain][t][16]
    u16*   Qb    = (u16*)  (ws +  78 * MB);   //  4 MB (dead after QK^T)
    float* Pmat  = (float*)(ws +  78 * MB);   //  4 MB aliases Qb
    u16*   Kb    = (u16*)  (ws +  82 * MB);   //  4 MB (dead after QK^T)
    float* evec  = (float*)(ws +  82 * MB);   // 256 KB aliases Kb
    float* sIn   = (float*)(ws +  82 * MB + 256 * 1024); // 256 KB
    u16*   Vb    = (u16*)  (ws +  86 * MB);   //  4 MB (dead after transpose)
    u16*   Vt    = (u16*)  (ws +  90 * MB);   //  4 MB (dead after PV)
    u16*   S     = (u16*)  (ws +  94 * MB);   // 64 MB (dead after PV)
    u16*   omat  = (u16*)  (ws + 158 * MB);   //  4 MB (dead after attn_out)
    u16*   gates = (u16*)  (ws +  94 * MB);   // 68 MB aliases S+omat
    u16*   hout  = (u16*)  (ws + 162 * MB);   //  4 MB (end: 166 MB)
    (void)in_sizes; (void)n_in; (void)out_size; (void)ws_size;

    dim3 tb(32, 8);
    convT_all<<<dim3(736, 32), tb, 0, stream>>>(
        wqkv, wao, wv, wa, wop, wqkvT, waoT, waT, wopT);

    rmsnorm_k<<<2048, 256, 0, stream>>>(x, anw, h);
    // qkv GEMM with fused RoPE epilogue -> Qb, Kb, Vb directly
    gemm_bt<64, 128, 32, 6, false, false, 0><<<dim3(24, 32, 1), 256, 0, stream>>>(
        h, wqkvT, (void*)Qb, (void*)Kb, (void*)Vb, nullptr, 2048, 3072, 1024, 0, 0, 0);
    transpose_bf16_k<<<dim3(2, 32, 32), tb, 0, stream>>>(Vb, Vt, 1024, 64);

    // QK^T: K=64 -> BK=64, single staging round per block
    gemm_bt<128, 128, 64, 1, false, true, 0><<<dim3(8, 8, 32), 256, 0, stream>>>(
        Qb, Kb, (void*)S, nullptr, nullptr, nullptr, 1024, 1024, 64, 65536, 65536, 1048576);
    softmax_causal_k<<<8192, 256, 0, stream>>>(S);
    // PV: BM=64, BK=64
    gemm_bt<64, 64, 64, 2, true, false, 0><<<dim3(1, 16, 32), 256, 0, stream>>>(
        S, Vt, (void*)omat, nullptr, nullptr, nullptr, 1024, 64, 1024, 1048576, 65536, 0);

    gemm_bt<64, 128, 32, 0, false, false, 0><<<dim3(8, 32, 1), 256, 0, stream>>>(
        omat, waoT, (void*)x2, nullptr, nullptr, x, 2048, 1024, 1024, 0, 0, 0);
    rmsnorm_k<<<2048, 256, 0, stream>>>(x2, lnw, h2);

    // fused gates + w_v GEMM: 256x192 tile, 768 blocks = 3 exact rounds
    gemm256_gates<<<dim3(96, 8), 512, 0, stream>>>(h2, waT, gates, vvT);

    scan_p1<<<dim3(32, 128), 64, 0, stream>>>(gates, vvT, Pmat, evec);
    scan_comb<<<128, 64, 0, stream>>>(Pmat, evec, sIn);
    scan_p2<<<dim3(32, 128), 64, 0, stream>>>(gates, vvT, sIn, hout);

    gemm_bt<64, 128, 32, 0, false, false, 0><<<dim3(8, 32, 1), 256, 0, stream>>>(
        hout, wopT, d_out, nullptr, nullptr, x2, 2048, 1024, 1024, 0, 0, 0);
}

// Round 3
// 474.995 us; speedup vs baseline: 1.0780x; 1.0129x over previous
//
#include <hip/hip_runtime.h>

// HKSABlock on MI355X (gfx950). Round 10: gates GEMM sync-floor reduction.
// R9 post-mortem: swizzle works (0 bank conflicts), traffic ideal, but 8
// barriers/K-tile kept all 8 waves lockstep -> ~1000 cyc/phase sync stall
// (MfmaUtil 29%). Key fact: the kh-split is in COLUMNS of the same 8KB
// pieces, so regrouping phases by M-HALF gives dependency sets
// {B0,B1,B2,A0,A2} / {A1,A3} -> true sync floor is 2 barriers per K-tile.
// Per tile: phase A (mh0, full K=64, 24 MFMA) ... vmcnt(5)+barrier ...
// phase B (mh1, full K=64, 24 MFMA) ... vmcnt(2)+barrier. Counted-vmcnt
// ledger (7 pieces in flight, never drained to 0) unchanged. Waves drift
// freely between sync points -> m97-style implicit wave overlap.
// Everything else (qkv+RoPE GEMM, attention, scan) unchanged.
// B=2, T=1024, D=1024, NH=16, HD=64, H=64, M=16.

typedef unsigned short u16;
typedef unsigned int   u32;
typedef __bf16 bf16x8 __attribute__((ext_vector_type(8)));
typedef float  f32x4  __attribute__((ext_vector_type(4)));

#define B_  2
#define T_  1024
#define D_  1024
#define NH_ 16
#define HD_ 64
#define H_  64
#define M_  16

__device__ __forceinline__ float b2f(u16 u) {
    return __uint_as_float(((u32)u) << 16);
}
__device__ __forceinline__ u16 f2b(float f) {
    u32 u = __float_as_uint(f);
    u32 r = (u + 0x7FFFu + ((u >> 16) & 1u)) >> 16;  // RNE
    return (u16)r;
}
__device__ __forceinline__ float blo(u32 u) { return __uint_as_float(u << 16); }
__device__ __forceinline__ float bhi(u32 u) { return __uint_as_float(u & 0xFFFF0000u); }

// Async global->LDS, 16 B per lane. LDS dest must be wave-uniform base.
__device__ __forceinline__ void stage16(const void* gp, void* lp) {
    typedef __attribute__((address_space(1))) const unsigned int GU;
    typedef __attribute__((address_space(3))) unsigned int LU;
    __builtin_amdgcn_global_load_lds((GU*)gp, (LU*)lp, 16, 0, 0);
}

// ---------------------------------------------------------------------------
// Generic MFMA GEMM: C[M,N] = A[M,K] * Bt[N,K]^T  (A,Bt bf16 row-major).
// 4 waves: wr = w>>1 (m-half), wc = w&1 (n-half). MT = BM/32, NT = BN/32.
// MODE 0: C fp32 (+ optional fp32 addend). MODE 1: C bf16.
// MODE 2: bf16 scatter into o_mat[(b*T + row)*1024 + h*64 + col], z = b*16+h.
// MODE 6: qkv + fused RoPE. N=3072; region = n0>>10 (0=Q,1=K,2=V). Each wave
//         owns one head's 64 cols; RoPE pair (i,i+32) = acc nt and nt+2.
//         Writes Qb(Cout)/Kb(Cout2)/Vb(Cout3) bf16 in (b,h,t,d).
// CAUSAL: skip blocks with n0 > m0+BM-1. TRUNCK: K truncated to m0+BM.
// ---------------------------------------------------------------------------
template<int BM, int BN, int BK, int MODE, bool TRUNCK, bool CAUSAL, int SWZ>
__global__ __launch_bounds__(256) void gemm_bt(
    const u16* __restrict__ A, const u16* __restrict__ Bt,
    void* __restrict__ Cout, void* __restrict__ Cout2, void* __restrict__ Cout3,
    const float* __restrict__ addend,
    int M, int N, int K, long strideA, long strideB, long strideC)
{
    constexpr int MT = BM / 32;
    constexpr int NT = BN / 32;
    constexpr int KCH = BK / 8;                  // 16B slots per row
    const int z  = blockIdx.z;
    int bx = blockIdx.x, by = blockIdx.y;
    if (SWZ == 2) {
        int f = by * gridDim.x + bx;
        int xcd = f & 7, k = f >> 3;
        by = k & 15;                             // by innermost per XCD
        bx = xcd * (gridDim.x >> 3) + (k >> 4);  // band per XCD
    }
    const int m0 = by * BM;
    const int n0 = bx * BN;
    if (CAUSAL && n0 > m0 + BM - 1) return;
    const int Keff = TRUNCK ? (K < m0 + BM ? K : m0 + BM) : K;

    const u16* Ab = A  + (size_t)z * (size_t)strideA;
    const u16* Bb = Bt + (size_t)z * (size_t)strideB;

    __shared__ alignas(16) u16 As[BM * BK];
    __shared__ alignas(16) u16 Bs[BN * BK];

    const int tid  = threadIdx.x;
    const int lane = tid & 63, w = tid >> 6;
    const int wr = w >> 1, wc = w & 1;
    const int quad = lane >> 4, l16 = lane & 15;

    f32x4 acc[MT][NT] = {};

    constexpr int AITER = (BM * BK / 8) / 256;
    constexpr int BITER = (BN * BK / 8) / 256;

    for (int k0 = 0; k0 < Keff; k0 += BK) {
        #pragma unroll
        for (int it = 0; it < AITER; ++it) {
            int c = it * 256 + tid;
            int m = c / KCH, kc = c % KCH;
            stage16(Ab + (size_t)(m0 + m) * K + k0 + kc * 8,
                    &As[(it * 256 + w * 64) * 8]);
        }
        #pragma unroll
        for (int it = 0; it < BITER; ++it) {
            int c = it * 256 + tid;
            int n = c / KCH, kc = c % KCH;
            stage16(Bb + (size_t)(n0 + n) * K + k0 + kc * 8,
                    &Bs[(it * 256 + w * 64) * 8]);
        }
        __syncthreads();

        #pragma unroll
        for (int kk = 0; kk < BK; kk += 32) {
            bf16x8 af[MT], bfr[NT];
            #pragma unroll
            for (int mt = 0; mt < MT; ++mt)
                af[mt] = *(const bf16x8*)&As[(wr * (BM / 2) + mt * 16 + l16) * BK + kk + quad * 8];
            #pragma unroll
            for (int nt = 0; nt < NT; ++nt)
                bfr[nt] = *(const bf16x8*)&Bs[(wc * (BN / 2) + nt * 16 + l16) * BK + kk + quad * 8];
            #pragma unroll
            for (int mt = 0; mt < MT; ++mt)
                #pragma unroll
                for (int nt = 0; nt < NT; ++nt)
                    acc[mt][nt] = __builtin_amdgcn_mfma_f32_16x16x32_bf16(
                        af[mt], bfr[nt], acc[mt][nt], 0, 0, 0);
        }
        __syncthreads();
    }

    // Epilogue. C/D layout: col = lane&15, row = (lane>>4)*4 + reg  [m89]
    if (MODE == 6) {
        // dedicated RoPE epilogue (NT==4, BN==128 required)
        const int reg = n0 >> 10;                      // 0=Q, 1=K, 2=V
        const int hh  = ((n0 & 1023) >> 6) + wc;       // head
        #pragma unroll
        for (int mt = 0; mt < MT; ++mt) {
            #pragma unroll
            for (int r = 0; r < 4; ++r) {
                int row = m0 + wr * (BM / 2) + mt * 16 + quad * 4 + r;
                int t = row & (T_ - 1), bb = row >> 10;
                size_t obase = ((size_t)(bb * NH_ + hh) * T_ + t) * HD_;
                if (reg == 2) {
                    #pragma unroll
                    for (int nt = 0; nt < 4; ++nt)
                        ((u16*)Cout3)[obase + nt * 16 + l16] = f2b(acc[mt][nt][r]);
                } else {
                    u16* dst = (reg == 0) ? (u16*)Cout : (u16*)Cout2;
                    #pragma unroll
                    for (int nt = 0; nt < 2; ++nt) {
                        int i = nt * 16 + l16;
                        float ang = (float)t * exp2f(-(float)i * 0.41524101186092034f);
                        float sn, cs;
                        sincosf(ang, &sn, &cs);
                        float q1 = acc[mt][nt][r], q2 = acc[mt][nt + 2][r];
                        dst[obase + i]      = f2b(q1 * cs - q2 * sn);
                        dst[obase + i + 32] = f2b(q2 * cs + q1 * sn);
                    }
                }
            }
        }
        return;
    }
    #pragma unroll
    for (int mt = 0; mt < MT; ++mt) {
        #pragma unroll
        for (int nt = 0; nt < NT; ++nt) {
            #pragma unroll
            for (int r = 0; r < 4; ++r) {
                int row = m0 + wr * (BM / 2) + mt * 16 + quad * 4 + r;
                int col = n0 + wc * (BN / 2) + nt * 16 + l16;
                float val = acc[mt][nt][r];
                if (MODE == 0) {
                    if (addend) val += addend[(size_t)row * N + col];
                    ((float*)Cout)[(size_t)z * (size_t)strideC + (size_t)row * N + col] = val;
                } else if (MODE == 1) {
                    ((u16*)Cout)[(size_t)z * (size_t)strideC + (size_t)row * N + col] = f2b(val);
                } else if (MODE == 2) {
                    size_t idx = ((size_t)(z >> 4) * T_ + row) * (size_t)D_ + (z & 15) * HD_ + col;
                    ((u16*)Cout)[idx] = f2b(val);
                }
            }
        }
    }
}

// ---------------------------------------------------------------------------
// gates+w_v GEMM: C[2048,18432] = h2[2048,1024] x waT[18432,1024]^T.
// 256x192 tile, grid 96x8 = 768 blocks = exactly 3 rounds of 256 CUs.
// 8 waves (wr=w>>2, wc=w&3), wave tile 128x48. LDS 112 KB -> 1 block/CU.
// K-tile BK=64 staged as 7 pieces of 8 KB. The kh split is COLUMNS of the
// same pieces, so phases are grouped by M-HALF:
//   phase A: mh0 x K=64 (24 MFMA), needs {B0,B1,B2,A0,A2}; stages those of t+1
//   vmcnt(5)+barrier  (A1,A3 of cur now visible to all waves)
//   phase B: mh1 x K=64 (24 MFMA), needs {A1,A3}; stages those of t+1
//   vmcnt(2)+barrier  ({B*,A0,A2} of t+1 visible)
// 2 barriers/K-tile (vs 8 in R9); waves drift between sync points so one
// wave's MFMA covers another's stage/ds_read. vmcnt never 0 in loop.
// Swizzle: 16B slot phys = logical ^ (row&7); inverse-swizzled global
// source + swizzled read (0 bank conflicts, verified R9).
// Epilogue: cg<1088 -> gates [chain][t][272] bf16; else vvT fp32.
// ---------------------------------------------------------------------------
__global__ __launch_bounds__(512, 2) void gemm256_gates(
    const u16* __restrict__ A, const u16* __restrict__ Bt,
    u16* __restrict__ gates, float* __restrict__ vvT)
{
    constexpr int K = 1024;
    constexpr int NTILE = 16;                    // K / 64

    // bijective XCD swizzle: 768 blocks, 96 per XCD = 12 bx x 8 by, by innermost
    const int f = blockIdx.y * gridDim.x + blockIdx.x;
    const int xcd = f & 7, k = f >> 3;           // k in [0,96)
    const int by = k & 7;
    const int bx = xcd * 12 + (k >> 3);
    const int m0 = by * 256;
    const int n0 = bx * 192;

    __shared__ alignas(16) u16 sA[2][256 * 64];  // 64 KB
    __shared__ alignas(16) u16 sB[2][192 * 64];  // 48 KB

    const int tid  = threadIdx.x;                // 0..511
    const int lane = tid & 63, w = tid >> 6;     // 8 waves
    const int wr = w >> 2, wc = w & 3;           // 2 x 4 wave grid
    const int quad = lane >> 4, l16 = lane & 15;

    // staging: thread t handles row (t>>3) of each 64-row piece, physical
    // 16B slot (t&7); global source slot = (t&7) ^ (row&7)  (involution).
    const int colOff = (((tid & 7) ^ ((tid >> 3) & 7)) * 8);
    const u16* pA = A  + (size_t)(m0 + (tid >> 3)) * K + colOff;
    const u16* pB = Bt + (size_t)(n0 + (tid >> 3)) * K + colOff;
    const int wbase = (tid >> 6) * 512;          // wave-uniform LDS dest (u16)

    // ds-read bases (u16): row*64 + phys_slot*8; phys = (quad + 4*kh) ^ (l16&7)
    const int sq0 = quad ^ (l16 & 7);
    const int sq1 = sq0 ^ 4;
    const int aoff0 = (wr * 128 + l16) * 64 + sq0 * 8;   // mh0 rows, kh0 slots
    const int aoff1 = (wr * 128 + l16) * 64 + sq1 * 8;   // mh0 rows, kh1 slots
    const int boff0 = (wc * 48  + l16) * 64 + sq0 * 8;
    const int boff1 = (wc * 48  + l16) * 64 + sq1 * 8;

    f32x4 acc[2][4][3] = {};                     // [mh][mt][nt]

    u16* sAc = sA[0]; u16* sAn = sA[1];
    u16* sBc = sB[0]; u16* sBn = sB[1];

    // prologue: stage tile 0, ledger order B0,B1,B2,A0,A2 | A1,A3
    stage16(pB,                    sBc + wbase);
    stage16(pB + (size_t) 64 * K,  sBc +  4096 + wbase);
    stage16(pB + (size_t)128 * K,  sBc +  8192 + wbase);
    stage16(pA,                    sAc + wbase);
    stage16(pA + (size_t)128 * K,  sAc +  8192 + wbase);
    stage16(pA + (size_t) 64 * K,  sAc +  4096 + wbase);
    stage16(pA + (size_t)192 * K,  sAc + 12288 + wbase);
    asm volatile("s_waitcnt vmcnt(2)" ::: "memory");   // B*,A0,A2 landed
    __builtin_amdgcn_s_barrier();

#define MFMA12(MH, AF, BF)                                           \
    __builtin_amdgcn_s_setprio(1);                                   \
    { _Pragma("unroll") for (int mt = 0; mt < 4; ++mt) {             \
        _Pragma("unroll") for (int nt = 0; nt < 3; ++nt)             \
          acc[MH][mt][nt] = __builtin_amdgcn_mfma_f32_16x16x32_bf16( \
              AF[mt], BF[nt], acc[MH][mt][nt], 0, 0, 0); } }         \
    __builtin_amdgcn_s_setprio(0);

    #pragma unroll 1
    for (int t = 0; t < NTILE; ++t) {
        const size_t kc = (size_t)((t < NTILE - 1 ? t + 1 : t) * 64); // next tile K
        bf16x8 af[4], ag[4], bfr[3], bgr[3];

        // ======== phase A: mh0, full K=64; stage B0,B1,B2,A0,A2 of next ====
        bfr[0] = *(const bf16x8*)&sBc[boff0];
        bfr[1] = *(const bf16x8*)&sBc[boff0 + 1024];
        bfr[2] = *(const bf16x8*)&sBc[boff0 + 2048];
        af[0]  = *(const bf16x8*)&sAc[aoff0];
        af[1]  = *(const bf16x8*)&sAc[aoff0 + 1024];
        af[2]  = *(const bf16x8*)&sAc[aoff0 + 2048];
        af[3]  = *(const bf16x8*)&sAc[aoff0 + 3072];
        stage16(pB + kc,                   sBn + wbase);
        stage16(pB + (size_t) 64 * K + kc, sBn + 4096 + wbase);
        stage16(pB + (size_t)128 * K + kc, sBn + 8192 + wbase);
        MFMA12(0, af, bfr)
        bgr[0] = *(const bf16x8*)&sBc[boff1];
        bgr[1] = *(const bf16x8*)&sBc[boff1 + 1024];
        bgr[2] = *(const bf16x8*)&sBc[boff1 + 2048];
        ag[0]  = *(const bf16x8*)&sAc[aoff1];
        ag[1]  = *(const bf16x8*)&sAc[aoff1 + 1024];
        ag[2]  = *(const bf16x8*)&sAc[aoff1 + 2048];
        ag[3]  = *(const bf16x8*)&sAc[aoff1 + 3072];
        stage16(pA + kc,                   sAn + wbase);
        stage16(pA + (size_t)128 * K + kc, sAn + 8192 + wbase);
        MFMA12(0, ag, bgr)
        // mid-tile sync: A1,A3 of cur landed & visible
        asm volatile("s_waitcnt vmcnt(5)" ::: "memory");
        __builtin_amdgcn_s_barrier();

        // ======== phase B: mh1, full K=64; stage A1,A3 of next =============
        af[0]  = *(const bf16x8*)&sAc[aoff0 + 4096];
        af[1]  = *(const bf16x8*)&sAc[aoff0 + 5120];
        af[2]  = *(const bf16x8*)&sAc[aoff0 + 6144];
        af[3]  = *(const bf16x8*)&sAc[aoff0 + 7168];
        stage16(pA + (size_t) 64 * K + kc, sAn +  4096 + wbase);
        stage16(pA + (size_t)192 * K + kc, sAn + 12288 + wbase);
        MFMA12(1, af, bfr)
        ag[0]  = *(const bf16x8*)&sAc[aoff1 + 4096];
        ag[1]  = *(const bf16x8*)&sAc[aoff1 + 5120];
        ag[2]  = *(const bf16x8*)&sAc[aoff1 + 6144];
        ag[3]  = *(const bf16x8*)&sAc[aoff1 + 7168];
        MFMA12(1, ag, bgr)
        // end-tile sync: B*,A0,A2 of next landed & visible
        asm volatile("s_waitcnt vmcnt(2)" ::: "memory");
        __builtin_amdgcn_s_barrier();

        u16* tp;
        tp = sAc; sAc = sAn; sAn = tp;
        tp = sBc; sBc = sBn; sBn = tp;
    }
#undef MFMA12

    // Epilogue: row = m0 + wr*128 + mh*64 + mt*16 + quad*4 + r
    //           col-group cg = bx*12 + wc*3 + nt  (lane-uniform), col = cg*16+l16
    const int cgbase = bx * 12 + wc * 3;
    #pragma unroll
    for (int mh = 0; mh < 2; ++mh) {
        #pragma unroll
        for (int mt = 0; mt < 4; ++mt) {
            #pragma unroll
            for (int r = 0; r < 4; ++r) {
                int row = m0 + wr * 128 + mh * 64 + mt * 16 + quad * 4 + r;
                int tt = row & (T_ - 1), bb = row >> 10;
                #pragma unroll
                for (int nt = 0; nt < 3; ++nt) {
                    int cg = cgbase + nt;
                    float val = acc[mh][mt][nt][r];
                    if (cg >= 1088) {
                        vvT[(((size_t)(bb * 64 + (cg - 1088))) * T_ + tt) * 16 + l16] = val;
                    } else {
                        int hh = cg / 17, rem = cg - hh * 17;
                        gates[(((size_t)(bb * 64 + hh)) * T_ + tt) * 272 + rem * 16 + l16] = f2b(val);
                    }
                }
            }
        }
    }
}

// ---------------------------------------------------------------------------
__global__ __launch_bounds__(256) void rmsnorm_k(
    const float* __restrict__ x, const float* __restrict__ w, u16* __restrict__ out)
{
    const int row = blockIdx.x, tid = threadIdx.x;
    float4 v = ((const float4*)(x + (size_t)row * D_))[tid];
    float ss = v.x * v.x + v.y * v.y + v.z * v.z + v.w * v.w;
    #pragma unroll
    for (int o = 32; o >= 1; o >>= 1) ss += __shfl_xor(ss, o, 64);
    __shared__ float red[4];
    if ((tid & 63) == 0) red[tid >> 6] = ss;
    __syncthreads();
    ss = red[0] + red[1] + red[2] + red[3];
    float scale = rsqrtf(ss * (1.0f / D_) + 1e-5f);
    float4 wv = ((const float4*)w)[tid];
    ushort4 o4;
    o4.x = f2b(v.x * scale * wv.x);
    o4.y = f2b(v.y * scale * wv.y);
    o4.z = f2b(v.z * scale * wv.z);
    o4.w = f2b(v.w * scale * wv.w);
    ((ushort4*)(out + (size_t)row * D_))[tid] = o4;
}

// ---------------------------------------------------------------------------
// All weight converts in one launch. Segments by blockIdx.x (all R=1024):
//   [0,96)   wqkv C=3072 -> wqkvT
//   [96,128) wao  C=1024 -> waoT
//   [128,160)wv   C=1024 -> waT + 17408*1024 (contiguous with waT)
//   [160,704)wa   C=17408-> waT
//   [704,736)wop  C=1024 -> wopT
// ---------------------------------------------------------------------------
__global__ void convT_all(
    const float* __restrict__ wqkv, const float* __restrict__ wao,
    const float* __restrict__ wv,   const float* __restrict__ wa,
    const float* __restrict__ wop,
    u16* __restrict__ wqkvT, u16* __restrict__ waoT,
    u16* __restrict__ waT,   u16* __restrict__ wopT)
{
    const int x = blockIdx.x;
    const float* in; u16* out; int C, xb;
    if (x < 96)       { in = wqkv; out = wqkvT; C = 3072;  xb = x; }
    else if (x < 128) { in = wao;  out = waoT;  C = 1024;  xb = x - 96; }
    else if (x < 160) { in = wv;   out = waT + (size_t)17408 * 1024; C = 1024; xb = x - 128; }
    else if (x < 704) { in = wa;   out = waT;   C = 17408; xb = x - 160; }
    else              { in = wop;  out = wopT;  C = 1024;  xb = x - 704; }
    constexpr int R = 1024;
    __shared__ float tile[32][33];
    const int c0 = xb * 32, r0 = blockIdx.y * 32;
    const int tx = threadIdx.x, ty = threadIdx.y;
    #pragma unroll
    for (int k = 0; k < 4; ++k)
        tile[ty + 8 * k][tx] = in[(size_t)(r0 + ty + 8 * k) * C + c0 + tx];
    __syncthreads();
    #pragma unroll
    for (int k = 0; k < 4; ++k)
        out[(size_t)(c0 + ty + 8 * k) * R + r0 + tx] = f2b(tile[tx][ty + 8 * k]);
}

__global__ void transpose_bf16_k(const u16* __restrict__ in_, u16* __restrict__ out_, int R, int C)
{
    __shared__ u16 tile[32][33];
    const u16* in = in_ + (size_t)blockIdx.z * R * C;
    u16* out      = out_ + (size_t)blockIdx.z * R * C;
    const int c0 = blockIdx.x * 32, r0 = blockIdx.y * 32;
    const int tx = threadIdx.x, ty = threadIdx.y;
    #pragma unroll
    for (int k = 0; k < 4; ++k)
        tile[ty + 8 * k][tx] = in[(size_t)(r0 + ty + 8 * k) * C + c0 + tx];
    __syncthreads();
    #pragma unroll
    for (int k = 0; k < 4; ++k)
        out[(size_t)(c0 + ty + 8 * k) * R + r0 + tx] = tile[tx][ty + 8 * k];
}

// ---------------------------------------------------------------------------
// Causal softmax, wave-per-row (4 rows/block). Only k < kmax = roundup(t+1,64)
// is read/written (PV's TRUNCK reads exactly that range).
// ---------------------------------------------------------------------------
__global__ __launch_bounds__(256) void softmax_causal_k(u16* __restrict__ S)
{
    const int w = threadIdx.x >> 6, lane = threadIdx.x & 63;
    const int z = blockIdx.x * 4 + w;
    const int t = z & (T_ - 1);
    u16* row = S + (size_t)z * T_;
    const int n = t + 1;
    const int kmax = (t & ~63) + 64;
    const int kb = lane * 4;
    float v[4][4];
    float mx = -1e30f;
    #pragma unroll
    for (int it = 0; it < 4; ++it) {
        int k = it * 256 + kb;
        if (k < kmax) {
            uint2 d = *(const uint2*)(row + k);
            v[it][0] = (k + 0 < n) ? blo(d.x) * 0.125f : -1e30f;
            v[it][1] = (k + 1 < n) ? bhi(d.x) * 0.125f : -1e30f;
            v[it][2] = (k + 2 < n) ? blo(d.y) * 0.125f : -1e30f;
            v[it][3] = (k + 3 < n) ? bhi(d.y) * 0.125f : -1e30f;
        } else {
            v[it][0] = v[it][1] = v[it][2] = v[it][3] = -1e30f;
        }
        mx = fmaxf(mx, fmaxf(fmaxf(v[it][0], v[it][1]), fmaxf(v[it][2], v[it][3])));
    }
    #pragma unroll
    for (int o = 32; o >= 1; o >>= 1) mx = fmaxf(mx, __shfl_xor(mx, o, 64));
    float sum = 0.f;
    #pragma unroll
    for (int it = 0; it < 4; ++it)
        #pragma unroll
        for (int j = 0; j < 4; ++j) {
            float e = (v[it][j] > -1e29f) ? __expf(v[it][j] - mx) : 0.f;
            v[it][j] = e;
            sum += e;
        }
    #pragma unroll
    for (int o = 32; o >= 1; o >>= 1) sum += __shfl_xor(sum, o, 64);
    float inv = 1.0f / sum;
    #pragma unroll
    for (int it = 0; it < 4; ++it) {
        int k = it * 256 + kb;
        if (k < kmax) {
            uint2 d;
            d.x = (u32)f2b(v[it][0] * inv) | ((u32)f2b(v[it][1] * inv) << 16);
            d.y = (u32)f2b(v[it][2] * inv) | ((u32)f2b(v[it][3] * inv) << 16);
            *(uint2*)(row + k) = d;
        }
    }
}

// ---------------------------------------------------------------------------
// Scan-chunk prep (shared by p1/p2): raw gate logits for a 32-step chunk in
// glds (32 x 16 rows x 17 bf16 @ 34 B). Softmax each row, repack the 16
// A-entries in place to (st*16+i)*32 B (bf16), scale vlds (v -> a0*v).
// ---------------------------------------------------------------------------
__device__ __forceinline__ void scan_prep(u16* glds, float* vlds, int lane)
{
    #pragma unroll
    for (int rnd = 0; rnd < 2; ++rnd) {
        float p[4][17];
        #pragma unroll
        for (int j = 0; j < 4; ++j) {
            int r = rnd * 256 + j * 64 + lane;
            const u16* g = &glds[r * 17];
            float vv[17];
            float mx = -1e30f;
            #pragma unroll
            for (int tt = 0; tt < 17; ++tt) { vv[tt] = b2f(g[tt]); mx = fmaxf(mx, vv[tt]); }
            float s = 0.f;
            #pragma unroll
            for (int tt = 0; tt < 17; ++tt) { vv[tt] = __expf(vv[tt] - mx); s += vv[tt]; }
            float inv = 1.0f / s;
            #pragma unroll
            for (int tt = 0; tt < 17; ++tt) p[j][tt] = vv[tt] * inv;
        }
        __syncthreads();
        #pragma unroll
        for (int j = 0; j < 4; ++j) {
            int r = rnd * 256 + j * 64 + lane;
            uint4 w0, w1;
            w0.x = (u32)f2b(p[j][1])  | ((u32)f2b(p[j][2])  << 16);
            w0.y = (u32)f2b(p[j][3])  | ((u32)f2b(p[j][4])  << 16);
            w0.z = (u32)f2b(p[j][5])  | ((u32)f2b(p[j][6])  << 16);
            w0.w = (u32)f2b(p[j][7])  | ((u32)f2b(p[j][8])  << 16);
            w1.x = (u32)f2b(p[j][9])  | ((u32)f2b(p[j][10]) << 16);
            w1.y = (u32)f2b(p[j][11]) | ((u32)f2b(p[j][12]) << 16);
            w1.z = (u32)f2b(p[j][13]) | ((u32)f2b(p[j][14]) << 16);
            w1.w = (u32)f2b(p[j][15]) | ((u32)f2b(p[j][16]) << 16);
            ((uint4*)glds)[r * 2]     = w0;
            ((uint4*)glds)[r * 2 + 1] = w1;
            vlds[r] *= p[j][0];
        }
        __syncthreads();
    }
}

// ---------------------------------------------------------------------------
// scan pass 1: per chunk of 32 steps compute P_c = A_31..A_0, e_c.
// ---------------------------------------------------------------------------
__global__ __launch_bounds__(64) void scan_p1(
    const u16* __restrict__ gates, const float* __restrict__ vvT,
    float* __restrict__ Pmat, float* __restrict__ evec)
{
    const int c = blockIdx.x, chain = blockIdx.y;
    const int lane = threadIdx.x;
    const int i = lane >> 2, q = lane & 3;
    __shared__ alignas(16) u16   glds[32 * 272];
    __shared__ alignas(16) float vlds[32 * 16];
    __shared__ alignas(16) float Pb[2][256];
    __shared__ float slds[16];

    const char* gbase = (const char*)(gates + ((size_t)chain * T_ + c * 32) * 272);
    #pragma unroll
    for (int it = 0; it < 17; ++it)
        stage16(gbase + it * 1024 + lane * 16, (char*)glds + it * 1024);
    const char* vbase = (const char*)(vvT + ((size_t)chain * T_ + c * 32) * 16);
    #pragma unroll
    for (int it = 0; it < 2; ++it)
        stage16(vbase + it * 1024 + lane * 16, (char*)vlds + it * 1024);
    __syncthreads();

    scan_prep(glds, vlds, lane);

    {
        f32x4 idq;
        #pragma unroll
        for (int m = 0; m < 4; ++m) idq[m] = (i == q * 4 + m) ? 1.f : 0.f;
        *(f32x4*)&Pb[0][i * 16 + q * 4] = idq;
    }
    f32x4 e4[4] = {};
    f32x4 np = {};
    float neLast = 0.f;
    int cur = 0;

    for (int st = 0; st < 32; ++st) {
        const uint4* rp = (const uint4*)((const char*)glds + (st * 16 + i) * 32);
        uint4 d0 = rp[0], d1 = rp[1];
        float ar[16];
        ar[0]  = blo(d0.x); ar[1]  = bhi(d0.x);
        ar[2]  = blo(d0.y); ar[3]  = bhi(d0.y);
        ar[4]  = blo(d0.z); ar[5]  = bhi(d0.z);
        ar[6]  = blo(d0.w); ar[7]  = bhi(d0.w);
        ar[8]  = blo(d1.x); ar[9]  = bhi(d1.x);
        ar[10] = blo(d1.y); ar[11] = bhi(d1.y);
        ar[12] = blo(d1.z); ar[13] = bhi(d1.z);
        ar[14] = blo(d1.w); ar[15] = bhi(d1.w);

        f32x4 pk[16];
        #pragma unroll
        for (int k = 0; k < 16; ++k)
            pk[k] = *(const f32x4*)&Pb[cur][k * 16 + q * 4];

        f32x4 a = pk[0] * ar[0];
        #pragma unroll
        for (int k = 1; k < 16; ++k) a += pk[k] * ar[k];
        np = a;

        float ne0 = ar[0] * e4[0][0] + ar[1] * e4[0][1] + ar[2] * e4[0][2] + ar[3] * e4[0][3];
        float ne1 = ar[4] * e4[1][0] + ar[5] * e4[1][1] + ar[6] * e4[1][2] + ar[7] * e4[1][3];
        float ne2 = ar[8] * e4[2][0] + ar[9] * e4[2][1] + ar[10] * e4[2][2] + ar[11] * e4[2][3];
        float ne3 = ar[12] * e4[3][0] + ar[13] * e4[3][1] + ar[14] * e4[3][2] + ar[15] * e4[3][3];
        float ne = (ne0 + ne1) + (ne2 + ne3) + vlds[st * 16 + i];

        *(f32x4*)&Pb[cur ^ 1][i * 16 + q * 4] = np;
        if (q == 0) slds[i] = ne;
        #pragma unroll
        for (int m = 0; m < 4; ++m) e4[m] = *(const f32x4*)&slds[m * 4];
        neLast = ne;
        cur ^= 1;
    }

    float* Pd = Pmat + ((size_t)chain * 32 + c) * 256;
    *(f32x4*)&Pd[i * 16 + q * 4] = np;
    if (q == 0) evec[((size_t)chain * 32 + c) * 16 + i] = neLast;
}

// ---------------------------------------------------------------------------
// scan pass 2: per chain, sequentially combine 32 chunks; sIn[c] = entry state.
// ---------------------------------------------------------------------------
__global__ __launch_bounds__(64) void scan_comb(
    const float* __restrict__ Pmat, const float* __restrict__ evec, float* __restrict__ sIn)
{
    const int chain = blockIdx.x;
    const int lane = threadIdx.x;
    const int i = lane >> 2, q = lane & 3;
    __shared__ alignas(16) float Pl[32 * 256];
    __shared__ alignas(16) float El[32 * 16];
    __shared__ float slds[16];

    const char* Pg = (const char*)(Pmat + (size_t)chain * 32 * 256);
    #pragma unroll
    for (int it = 0; it < 32; ++it)
        stage16(Pg + it * 1024 + lane * 16, (char*)Pl + it * 1024);
    const char* Eg = (const char*)(evec + (size_t)chain * 32 * 16);
    #pragma unroll
    for (int it = 0; it < 2; ++it)
        stage16(Eg + it * 1024 + lane * 16, (char*)El + it * 1024);
    __syncthreads();

    f32x4 s4[4] = {};
    if (q == 0) sIn[((size_t)chain * 32 + 0) * 16 + i] = 0.f;
    for (int cc = 0; cc < 32; ++cc) {
        f32x4 pr[4];
        #pragma unroll
        for (int m = 0; m < 4; ++m)
            pr[m] = *(const f32x4*)&Pl[cc * 256 + i * 16 + m * 4];
        float ne = 0.f;
        #pragma unroll
        for (int k = 0; k < 16; ++k) ne += pr[k >> 2][k & 3] * s4[k >> 2][k & 3];
        ne += El[cc * 16 + i];
        if (q == 0) {
            slds[i] = ne;
            if (cc < 31) sIn[((size_t)chain * 32 + cc + 1) * 16 + i] = ne;
        }
        #pragma unroll
        for (int m = 0; m < 4; ++m) s4[m] = *(const f32x4*)&slds[m * 4];
    }
}

// ---------------------------------------------------------------------------
// scan pass 3: replay each chunk from its entry state, write h_out.
// ---------------------------------------------------------------------------
__global__ __launch_bounds__(64) void scan_p2(
    const u16* __restrict__ gates, const float* __restrict__ vvT,
    const float* __restrict__ sIn, u16* __restrict__ hout)
{
    const int c = blockIdx.x, chain = blockIdx.y;
    const int b = chain >> 6, hh = chain & 63;
    const int lane = threadIdx.x;
    const int i = lane >> 2, q = lane & 3;
    __shared__ alignas(16) u16   glds[32 * 272];
    __shared__ alignas(16) float vlds[32 * 16];
    __shared__ float slds[16];

    const char* gbase = (const char*)(gates + ((size_t)chain * T_ + c * 32) * 272);
    #pragma unroll
    for (int it = 0; it < 17; ++it)
        stage16(gbase + it * 1024 + lane * 16, (char*)glds + it * 1024);
    const char* vbase = (const char*)(vvT + ((size_t)chain * T_ + c * 32) * 16);
    #pragma unroll
    for (int it = 0; it < 2; ++it)
        stage16(vbase + it * 1024 + lane * 16, (char*)vlds + it * 1024);
    __syncthreads();

    scan_prep(glds, vlds, lane);

    const float* sp = sIn + ((size_t)chain * 32 + c) * 16;
    f32x4 s4[4];
    #pragma unroll
    for (int m = 0; m < 4; ++m) s4[m] = *(const f32x4*)(sp + m * 4);

    u16* hbase = hout + ((size_t)(b * T_ + c * 32)) * D_ + hh * 16;
    for (int st = 0; st < 32; ++st) {
        const uint4* rp = (const uint4*)((const char*)glds + (st * 16 + i) * 32);
        uint4 d0 = rp[0], d1 = rp[1];
        float ne0 = blo(d0.x) * s4[0][0] + bhi(d0.x) * s4[0][1]
                  + blo(d0.y) * s4[0][2] + bhi(d0.y) * s4[0][3];
        float ne1 = blo(d0.z) * s4[1][0] + bhi(d0.z) * s4[1][1]
                  + blo(d0.w) * s4[1][2] + bhi(d0.w) * s4[1][3];
        float ne2 = blo(d1.x) * s4[2][0] + bhi(d1.x) * s4[2][1]
                  + blo(d1.y) * s4[2][2] + bhi(d1.y) * s4[2][3];
        float ne3 = blo(d1.z) * s4[3][0] + bhi(d1.z) * s4[3][1]
                  + blo(d1.w) * s4[3][2] + bhi(d1.w) * s4[3][3];
        float ne = (ne0 + ne1) + (ne2 + ne3) + vlds[st * 16 + i];
        if (q == 0) {
            slds[i] = ne;
            hbase[(size_t)st * D_ + i] = f2b(ne);
        }
        #pragma unroll
        for (int m = 0; m < 4; ++m) s4[m] = *(const f32x4*)&slds[m * 4];
    }
}

// ---------------------------------------------------------------------------
extern "C" void kernel_launch(void* const* d_in, const int* in_sizes, int n_in,
                              void* d_out, int out_size, void* d_ws, size_t ws_size,
                              hipStream_t stream)
{
    const float* x    = (const float*)d_in[0];
    const float* anw  = (const float*)d_in[1];
    const float* wqkv = (const float*)d_in[2];
    const float* wao  = (const float*)d_in[3];
    const float* lnw  = (const float*)d_in[4];
    const float* wv   = (const float*)d_in[5];
    const float* wa   = (const float*)d_in[6];
    const float* wop  = (const float*)d_in[7];

    char* ws = (char*)d_ws;
    const size_t MB = 1u << 20;
    u16*   h     = (u16*)  (ws +   0 * MB);   //  4 MB
    u16*   h2    = (u16*)  (ws +   4 * MB);   //  4 MB
    u16*   wqkvT = (u16*)  (ws +   8 * MB);   //  6 MB
    u16*   waoT  = (u16*)  (ws +  14 * MB);   //  2 MB
    u16*   wopT  = (u16*)  (ws +  16 * MB);   //  2 MB
    u16*   waT   = (u16*)  (ws +  18 * MB);   // 36 MB (wa 17408 rows + wv 1024 rows)
    float* x2    = (float*)(ws +  54 * MB);   //  8 MB
    float* vvT   = (float*)(ws +  62 * MB);   //  8 MB scan layout [chain][t][16]
    u16*   Qb    = (u16*)  (ws +  78 * MB);   //  4 MB (dead after QK^T)
    float* Pmat  = (float*)(ws +  78 * MB);   //  4 MB aliases Qb
    u16*   Kb    = (u16*)  (ws +  82 * MB);   //  4 MB (dead after QK^T)
    float* evec  = (float*)(ws +  82 * MB);   // 256 KB aliases Kb
    float* sIn   = (float*)(ws +  82 * MB + 256 * 1024); // 256 KB
    u16*   Vb    = (u16*)  (ws +  86 * MB);   //  4 MB (dead after transpose)
    u16*   Vt    = (u16*)  (ws +  90 * MB);   //  4 MB (dead after PV)
    u16*   S     = (u16*)  (ws +  94 * MB);   // 64 MB (dead after PV)
    u16*   omat  = (u16*)  (ws + 158 * MB);   //  4 MB (dead after attn_out)
    u16*   gates = (u16*)  (ws +  94 * MB);   // 68 MB aliases S+omat
    u16*   hout  = (u16*)  (ws + 162 * MB);   //  4 MB (end: 166 MB)
    (void)in_sizes; (void)n_in; (void)out_size; (void)ws_size;

    dim3 tb(32, 8);
    convT_all<<<dim3(736, 32), tb, 0, stream>>>(
        wqkv, wao, wv, wa, wop, wqkvT, waoT, waT, wopT);

    rmsnorm_k<<<2048, 256, 0, stream>>>(x, anw, h);
    // qkv GEMM with fused RoPE epilogue -> Qb, Kb, Vb directly
    gemm_bt<64, 128, 32, 6, false, false, 0><<<dim3(24, 32, 1), 256, 0, stream>>>(
        h, wqkvT, (void*)Qb, (void*)Kb, (void*)Vb, nullptr, 2048, 3072, 1024, 0, 0, 0);
    transpose_bf16_k<<<dim3(2, 32, 32), tb, 0, stream>>>(Vb, Vt, 1024, 64);

    // QK^T: K=64 -> BK=64, single staging round per block
    gemm_bt<128, 128, 64, 1, false, true, 0><<<dim3(8, 8, 32), 256, 0, stream>>>(
        Qb, Kb, (void*)S, nullptr, nullptr, nullptr, 1024, 1024, 64, 65536, 65536, 1048576);
    softmax_causal_k<<<8192, 256, 0, stream>>>(S);
    // PV: BM=64, BK=64
    gemm_bt<64, 64, 64, 2, true, false, 0><<<dim3(1, 16, 32), 256, 0, stream>>>(
        S, Vt, (void*)omat, nullptr, nullptr, nullptr, 1024, 64, 1024, 1048576, 65536, 0);

    gemm_bt<64, 128, 32, 0, false, false, 0><<<dim3(8, 32, 1), 256, 0, stream>>>(
        omat, waoT, (void*)x2, nullptr, nullptr, x, 2048, 1024, 1024, 0, 0, 0);
    rmsnorm_k<<<2048, 256, 0, stream>>>(x2, lnw, h2);

    // fused gates + w_v GEMM: 256x192 tile, 768 blocks, 2 barriers/K-tile
    gemm256_gates<<<dim3(96, 8), 512, 0, stream>>>(h2, waT, gates, vvT);

    scan_p1<<<dim3(32, 128), 64, 0, stream>>>(gates, vvT, Pmat, evec);
    scan_comb<<<128, 64, 0, stream>>>(Pmat, evec, sIn);
    scan_p2<<<dim3(32, 128), 64, 0, stream>>>(gates, vvT, sIn, hout);

    gemm_bt<64, 128, 32, 0, false, false, 0><<<dim3(8, 32, 1), 256, 0, stream>>>(
        hout, wopT, d_out, nullptr, nullptr, x2, 2048, 1024, 1024, 0, 0, 0);
}